// Round 3
// baseline (37230.939 us; speedup 1.0000x reference)
//
#include <hip/hip_runtime.h>
#include <math.h>

constexpr int BSZ  = 256;
constexpr int TLEN = 128;
constexpr int LLEN = 64;
constexpr int DH   = 512;
constexpr int EMBD = 128;
constexpr int ACTN = 129;
constexpr int HATT = 20;

typedef short bf16x8 __attribute__((ext_vector_type(8)));
typedef float f32x4  __attribute__((ext_vector_type(4)));

__device__ __forceinline__ short f2bf(float f) {
    unsigned u = __builtin_bit_cast(unsigned, f);
    u += 0x7fffu + ((u >> 16) & 1u);
    return (short)(u >> 16);
}
__device__ __forceinline__ float bf2f(short s) {
    unsigned u = ((unsigned)(unsigned short)s) << 16;
    return __builtin_bit_cast(float, u);
}

// ---------------------------------------------------------------------------
// Prep: fold attn_combine into LSTM1  W1f[n][k] = sum_m Wih1[n][m]*Wc[m][k]
// ---------------------------------------------------------------------------
__launch_bounds__(256)
__global__ void k_fold(const float* __restrict__ Wih1, const float* __restrict__ Wc,
                       float* __restrict__ W1f)
{
    __shared__ float at[64][33];
    __shared__ float bt[32][65];
    int tid = threadIdx.x;
    int tx = tid & 15, ty = tid >> 4;
    int n0 = blockIdx.x * 64, k0 = blockIdx.y * 64;
    float acc[4][4] = {};
    for (int m0 = 0; m0 < 512; m0 += 32) {
        for (int i = 0; i < 8; ++i) {
            int idx = tid + 256 * i;
            int nl = idx >> 5, ml = idx & 31;
            at[nl][ml] = Wih1[(size_t)(n0 + nl) * 512 + m0 + ml];
        }
        for (int i = 0; i < 8; ++i) {
            int idx = tid + 256 * i;
            int ml = idx >> 6, kl = idx & 63;
            bt[ml][kl] = Wc[(size_t)(m0 + ml) * 640 + k0 + kl];
        }
        __syncthreads();
        for (int m = 0; m < 32; ++m) {
            #pragma unroll
            for (int i = 0; i < 4; ++i) {
                float av = at[ty * 4 + i][m];
                #pragma unroll
                for (int j = 0; j < 4; ++j)
                    acc[i][j] += av * bt[m][tx * 4 + j];
            }
        }
        __syncthreads();
    }
    for (int i = 0; i < 4; ++i)
        for (int j = 0; j < 4; ++j)
            W1f[(size_t)(n0 + ty * 4 + i) * 640 + (k0 + tx * 4 + j)] = acc[i][j];
}

// ---------------------------------------------------------------------------
// Weight packs (MFMA fragment order; LSTM packs gate-interleave columns)
// element: (nn*KSTEPS + ks)*512 + lane*8 + i ; col n' = nn*16 + (lane&15),
// k = ks*32 + (lane>>4)*8 + i ; LSTM n_orig = (n'&3)*512 + (n'>>2)
// ---------------------------------------------------------------------------
__global__ void k_pack23(const float* __restrict__ Wih, const float* __restrict__ Whh,
                         short* __restrict__ pack)
{
    int idx = blockIdx.x * 256 + threadIdx.x;       // 262144
    int lane = idx & 63;
    int ks = (idx >> 6) & 31;
    int nn = idx >> 11;
    int np = nn * 16 + (lane & 15);
    int k  = ks * 32 + ((lane >> 4) << 3);
    int n  = (np & 3) * 512 + (np >> 2);
    const float* src = (k < 512) ? (Wih + (size_t)n * 512 + k)
                                 : (Whh + (size_t)n * 512 + (k - 512));
    short* dst = pack + (size_t)idx * 8;
    #pragma unroll
    for (int i = 0; i < 8; ++i) dst[i] = f2bf(src[i]);
}

__global__ void k_pack1(const float* __restrict__ W1f, const float* __restrict__ Whh1,
                        short* __restrict__ pack)
{
    int idx = blockIdx.x * 256 + threadIdx.x;       // 294912
    int lane = idx & 63;
    int tmp = idx >> 6;
    int ks = tmp % 36;
    int nn = tmp / 36;
    int np = nn * 16 + (lane & 15);
    int k  = ks * 32 + ((lane >> 4) << 3);
    int n  = (np & 3) * 512 + (np >> 2);
    const float* src = (k < 640) ? (W1f + (size_t)n * 640 + k)
                                 : (Whh1 + (size_t)n * 512 + (k - 640));
    short* dst = pack + (size_t)idx * 8;
    #pragma unroll
    for (int i = 0; i < 8; ++i) dst[i] = f2bf(src[i]);
}

__global__ void k_packh1(const float* __restrict__ Wl1, short* __restrict__ pack)
{
    int idx = blockIdx.x * 256 + threadIdx.x;       // 65536
    int lane = idx & 63;
    int ks = (idx >> 6) & 31;
    int nn = idx >> 11;                              // <32
    int np = nn * 16 + (lane & 15);                  // <512, no permute
    int k  = ks * 32 + ((lane >> 4) << 3);
    const float* src = Wl1 + (size_t)np * 1024 + k;
    short* dst = pack + (size_t)idx * 8;
    #pragma unroll
    for (int i = 0; i < 8; ++i) dst[i] = f2bf(src[i]);
}

__global__ void k_packh2(const float* __restrict__ Wl2, short* __restrict__ pack)
{
    int idx = blockIdx.x * 256 + threadIdx.x;       // 12288
    int lane = idx & 63;
    int ks = (idx >> 6) & 15;
    int nn = idx >> 10;                              // <12
    int np = nn * 16 + (lane & 15);                  // <192
    int k  = ks * 32 + ((lane >> 4) << 3);
    short* dst = pack + (size_t)idx * 8;
    if (np < ACTN) {
        const float* src = Wl2 + (size_t)np * 512 + k;
        #pragma unroll
        for (int i = 0; i < 8; ++i) dst[i] = f2bf(src[i]);
    } else {
        #pragma unroll
        for (int i = 0; i < 8; ++i) dst[i] = 0;
    }
}

// ---------------------------------------------------------------------------
// Permuted biases (b1p includes Wih1 @ bc)
// ---------------------------------------------------------------------------
__global__ void k_bias(const float* __restrict__ Wih1, const float* __restrict__ bc,
                       const float* bih1, const float* bhh1,
                       const float* bih2, const float* bhh2,
                       const float* bih3, const float* bhh3,
                       float* b1p, float* b2p, float* b3p)
{
    int cp = blockIdx.x * 256 + threadIdx.x;        // 2048
    int n = (cp & 3) * 512 + (cp >> 2);
    float s = bih1[n] + bhh1[n];
    for (int m = 0; m < 512; ++m) s += Wih1[(size_t)n * 512 + m] * bc[m];
    b1p[cp] = s;
    b2p[cp] = bih2[n] + bhh2[n];
    b3p[cp] = bih3[n] + bhh3[n];
}

__global__ void k_tr(float* __restrict__ dst, const float* __restrict__ src,
                     int R, int C, int sld, int dld)
{
    int idx = blockIdx.x * 256 + threadIdx.x;
    if (idx >= R * C) return;
    int c = idx / R, r = idx - c * R;
    dst[c * dld + r] = src[r * sld + c];
}

// ---------------------------------------------------------------------------
// ENCP[b][l][h] = enc[b][l][:] . Wa1[h][:512] + ba1[h]
// ---------------------------------------------------------------------------
__launch_bounds__(256)
__global__ void k_encp(const float* __restrict__ enc, const float* __restrict__ Wa1,
                       const float* __restrict__ ba1, float* __restrict__ ENCP)
{
    __shared__ float wa[HATT * 513];
    __shared__ float er[8][513];
    int b = blockIdx.x, tid = threadIdx.x;
    for (int idx = tid; idx < HATT * 512; idx += 256) {
        int h = idx >> 9, e = idx & 511;
        wa[h * 513 + e] = Wa1[h * 1024 + e];
    }
    __syncthreads();
    for (int c = 0; c < 8; ++c) {
        for (int i = 0; i < 16; ++i) {
            int idx = tid + 256 * i;
            int rr = idx >> 9, e = idx & 511;
            er[rr][e] = enc[((size_t)b * LLEN + c * 8 + rr) * 512 + e];
        }
        __syncthreads();
        if (tid < 8 * HATT) {
            int rr = tid & 7, h = tid >> 3;
            float s = 0.f;
            for (int e = 0; e < 512; ++e) s += er[rr][e] * wa[h * 513 + e];
            ENCP[((size_t)b * LLEN + c * 8 + rr) * HATT + h] = s + ba1[h];
        }
        __syncthreads();
    }
}

// ---------------------------------------------------------------------------
// ET[t][b][k] = bf16(embW[act[b][t-1]][k]); zeros at t=0
// ---------------------------------------------------------------------------
__global__ void k_embed(const int* __restrict__ act, const float* __restrict__ embW,
                        short* __restrict__ ET)
{
    int idx = blockIdx.x * 256 + threadIdx.x;       // 128*256*128
    int t = idx >> 15;
    int rem = idx & 32767;
    int b = rem >> 7, k = rem & 127;
    float v = 0.f;
    if (t > 0) v = embW[(size_t)act[b * TLEN + t - 1] * EMBD + k];
    ET[idx] = f2bf(v);
}

// enc -> bf16
__global__ void k_encb(const float* __restrict__ enc, short* __restrict__ ENCB)
{
    int i = blockIdx.x * 256 + threadIdx.x;         // x4 elems, 8192 blocks
    float4 v = *(const float4*)&enc[(size_t)i * 4];
    short4 o;
    o.x = f2bf(v.x); o.y = f2bf(v.y); o.z = f2bf(v.z); o.w = f2bf(v.w);
    *(short4*)&ENCB[(size_t)i * 4] = o;
}

// h/ctx init
__global__ void k_init(const float* __restrict__ eh,
                       short* h0, short* h1, short* h2, short* ctx)
{
    int i = blockIdx.x * 256 + threadIdx.x;         // 131072
    short hb = f2bf(eh[i]);
    h0[i] = hb; h1[i] = hb; h2[i] = hb; ctx[i] = 0;
}

// ---------------------------------------------------------------------------
// Persistent megakernel: 256 blocks x 512 threads, 1 block/CU (LDS-forced).
// LSTM weight slices live in LDS for all 128 steps; c-state lives in LDS.
// Grid sync: 8-counter monotonic-generation barrier, agent-scope atomics.
// ---------------------------------------------------------------------------
__device__ __forceinline__ void gstage(
    int KS,
    const short* wl,                    // LDS weight slice
    const float* __restrict__ biasp,
    const short* __restrict__ a0, int ld0, int e1,   // ks <  e1 -> a0
    const short* __restrict__ a1, int e2,            // ks <  e2 -> a1 (ld 512)
    const short* __restrict__ a2,                    // else     -> a2 (ld 512)
    float* cst, short* __restrict__ hout,
    float* gsc, int half, int nn, int tid)
{
    const int wave = tid >> 6, lane = tid & 63;
    const int rlane = lane & 15, kq = lane >> 4;
    const int arow = half * 128 + wave * 16 + rlane;
    f32x4 acc = {};
    #pragma unroll 4
    for (int ks = 0; ks < KS; ++ks) {
        int k0 = ks * 32 + kq * 8;
        const short* ap;
        if (ks < e1)      ap = a0 + (size_t)arow * ld0 + k0;
        else if (ks < e2) ap = a1 + (size_t)arow * 512 + (k0 - e1 * 32);
        else              ap = a2 + (size_t)arow * 512 + (k0 - e2 * 32);
        bf16x8 af = *(const bf16x8*)ap;
        bf16x8 bf = *(const bf16x8*)&wl[(ks * 64 + lane) * 8];
        acc = __builtin_amdgcn_mfma_f32_16x16x32_bf16(af, bf, acc, 0, 0, 0);
    }
    float bp = biasp[nn * 16 + rlane];
    #pragma unroll
    for (int r = 0; r < 4; ++r)
        gsc[(wave * 16 + kq * 4 + r) * 17 + rlane] = acc[r] + bp;
    __syncthreads();
    {
        int row = tid >> 2, jl = tid & 3;           // tid < 512
        float gi = gsc[row * 17 + jl * 4 + 0];
        float gf = gsc[row * 17 + jl * 4 + 1];
        float gg = gsc[row * 17 + jl * 4 + 2];
        float go = gsc[row * 17 + jl * 4 + 3];
        float c  = cst[tid];
        float si = 1.f / (1.f + __expf(-gi));
        float sf = 1.f / (1.f + __expf(-gf));
        float so = 1.f / (1.f + __expf(-go));
        float cn = sf * c + si * tanhf(gg);
        float hn = so * tanhf(cn);
        cst[tid] = cn;
        hout[(size_t)(half * 128 + row) * 512 + nn * 4 + jl] = f2bf(hn);
    }
    __syncthreads();
}

template<int KSTEPS, bool RELU>
__device__ __forceinline__ void headstage(
    const short* __restrict__ packw, const float* __restrict__ biasv,
    const short* __restrict__ a0, const short* __restrict__ a1, int e1,
    short* __restrict__ hidden, float* __restrict__ out, int t,
    float* gsc, int mg, int ng, int tid)
{
    const int wave = tid >> 6, lane = tid & 63;
    const int rlane = lane & 15, kq = lane >> 4;
    constexpr int PER = KSTEPS / 8;
    f32x4 acc[2] = {};
    #pragma unroll
    for (int i = 0; i < PER; ++i) {
        int ks = wave * PER + i;
        int k0 = ks * 32 + kq * 8;
        const short* src; int kk;
        if (ks < e1) { src = a0; kk = k0; }
        else         { src = a1; kk = k0 - e1 * 32; }
        bf16x8 bfr = *(const bf16x8*)&packw[((size_t)(ng * KSTEPS + ks) * 64 + lane) * 8];
        bf16x8 af0 = *(const bf16x8*)(src + (size_t)(mg * 32 + rlane) * 512 + kk);
        bf16x8 af1 = *(const bf16x8*)(src + (size_t)(mg * 32 + 16 + rlane) * 512 + kk);
        acc[0] = __builtin_amdgcn_mfma_f32_16x16x32_bf16(af0, bfr, acc[0], 0, 0, 0);
        acc[1] = __builtin_amdgcn_mfma_f32_16x16x32_bf16(af1, bfr, acc[1], 0, 0, 0);
    }
    #pragma unroll
    for (int mf = 0; mf < 2; ++mf)
        #pragma unroll
        for (int r = 0; r < 4; ++r)
            gsc[wave * 512 + mf * 256 + (kq * 4 + r) * 16 + rlane] = acc[mf][r];
    __syncthreads();
    {
        int pos = tid;                               // < 512
        float s = 0.f;
        #pragma unroll
        for (int w = 0; w < 8; ++w) s += gsc[w * 512 + pos];
        int mf = pos >> 8, rr = (pos >> 4) & 15, cc = pos & 15;
        int row = mg * 32 + mf * 16 + rr, col = ng * 16 + cc;
        if (RELU) {
            hidden[(size_t)row * 512 + col] = f2bf(fmaxf(s + biasv[col], 0.f));
        } else if (col < ACTN) {
            out[((size_t)row * TLEN + t) * ACTN + col] = s + biasv[col];
        }
    }
    __syncthreads();
}

__device__ __forceinline__ void attstage(
    const short* __restrict__ h2q, const short* __restrict__ ENCB,
    const float* __restrict__ ENCP, const float* __restrict__ WaHT,
    const float* __restrict__ Wa2, const float* __restrict__ ba2v,
    short* __restrict__ ctx,
    float* h2s, float* part, float* hp, float* sl, int b, int tid)
{
    h2s[tid] = bf2f(h2q[(size_t)b * 512 + tid]);
    __syncthreads();
    if (tid < 8 * HATT) {
        int h = tid % HATT, sg = tid / HATT;
        float s = 0.f;
        for (int e = sg * 64; e < sg * 64 + 64; ++e) s += h2s[e] * WaHT[e * HATT + h];
        part[sg * HATT + h] = s;
    }
    __syncthreads();
    if (tid < HATT) {
        float s = 0.f;
        #pragma unroll
        for (int sg = 0; sg < 8; ++sg) s += part[sg * HATT + tid];
        hp[tid] = s;
    }
    __syncthreads();
    if (tid < LLEN) {
        float s = ba2v[0];
        const float* ep = ENCP + ((size_t)b * LLEN + tid) * HATT;
        #pragma unroll
        for (int h = 0; h < HATT; ++h)
            s += fmaxf(ep[h] + hp[h], 0.f) * Wa2[h];
        float v = tanhf(s);
        float m = v;
        for (int o = 32; o; o >>= 1) m = fmaxf(m, __shfl_xor(m, o));
        float e = __expf(v - m);
        float ss = e;
        for (int o = 32; o; o >>= 1) ss += __shfl_xor(ss, o);
        sl[tid] = e / ss;
    }
    __syncthreads();
    {
        float a = 0.f;
        const short* eb = ENCB + (size_t)b * LLEN * 512 + tid;
        #pragma unroll 8
        for (int l = 0; l < LLEN; ++l) a += sl[l] * bf2f(eb[l * 512]);
        ctx[(size_t)b * 512 + tid] = f2bf(a);
    }
}

__launch_bounds__(512)
__global__ void k_mega(
    const short* __restrict__ pack1, const short* __restrict__ pack2,
    const short* __restrict__ pack3, const short* __restrict__ packh1,
    const short* __restrict__ packh2,
    const float* __restrict__ b1p, const float* __restrict__ b2p,
    const float* __restrict__ b3p, const float* __restrict__ bl1,
    const float* __restrict__ bl2,
    const short* __restrict__ ET, const short* __restrict__ ENCB,
    const float* __restrict__ ENCP, const float* __restrict__ WaHT,
    const float* __restrict__ Wa2, const float* __restrict__ ba2v,
    const float* __restrict__ enc_c,
    short* __restrict__ h0a, short* __restrict__ h0b,
    short* __restrict__ h1a, short* __restrict__ h1b,
    short* __restrict__ h2a, short* __restrict__ h2b,
    short* __restrict__ ctx, short* __restrict__ hidden,
    unsigned long long* __restrict__ bar,
    float* __restrict__ out)
{
    __shared__ short wlds[51200];        // 102.4 KB: W1|W2|W3 slices
    __shared__ float gsc[4096];          // 16 KB scratch (epilogue / reductions)
    __shared__ float cst[3 * 512];       // persistent c-state
    __shared__ float h2s[512];
    __shared__ float part[8 * HATT];
    __shared__ float hp[HATT];
    __shared__ float sl[LLEN];

    const int tid  = threadIdx.x;
    const int blk  = blockIdx.x;
    const int half = blk >> 7, nn = blk & 127;

    // --- park weight slices in LDS ---
    {
        const short* s1 = pack1 + (size_t)nn * 18432;
        const short* s2 = pack2 + (size_t)nn * 16384;
        const short* s3 = pack3 + (size_t)nn * 16384;
        for (int i = tid; i < 2304; i += 512)
            *(bf16x8*)&wlds[i * 8] = *(const bf16x8*)&s1[i * 8];
        for (int i = tid; i < 2048; i += 512) {
            *(bf16x8*)&wlds[18432 + i * 8] = *(const bf16x8*)&s2[i * 8];
            *(bf16x8*)&wlds[34816 + i * 8] = *(const bf16x8*)&s3[i * 8];
        }
    }
    // --- c-state init ---
    {
        int row = tid >> 2, jl = tid & 3;
        float cv = enc_c[(size_t)(half * 128 + row) * 512 + nn * 4 + jl];
        cst[tid] = cv; cst[512 + tid] = cv; cst[1024 + tid] = cv;
    }
    __syncthreads();

    int gen = 0;
    auto gbar = [&]() {
        ++gen;
        __syncthreads();
        if (tid == 0) {
            __threadfence();
            __hip_atomic_fetch_add(&bar[blk & 7], 1ull,
                                   __ATOMIC_RELEASE, __HIP_MEMORY_SCOPE_AGENT);
        }
        if (tid < 64) {
            unsigned long long target = 256ull * (unsigned long long)gen;
            for (;;) {
                unsigned long long v = (tid < 8)
                    ? __hip_atomic_load(&bar[tid], __ATOMIC_ACQUIRE,
                                        __HIP_MEMORY_SCOPE_AGENT)
                    : 0ull;
                v += __shfl_xor(v, 1);
                v += __shfl_xor(v, 2);
                v += __shfl_xor(v, 4);
                if (__shfl(v, 0) >= target) break;
                __builtin_amdgcn_s_sleep(2);
            }
        }
        __syncthreads();
        __threadfence();
    };

    short* h0p[2] = { h0a, h0b };
    short* h1p[2] = { h1a, h1b };
    short* h2p[2] = { h2a, h2b };

    for (int t = 0; t < TLEN; ++t) {
        int p = t & 1, q = p ^ 1;
        // LSTM1: A = [ET(t) | ctx | h0_old], K=1152
        gstage(36, wlds, b1p,
               ET + (size_t)t * BSZ * EMBD, 128, 4, ctx, 20, h0p[p],
               cst, h0p[q], gsc, half, nn, tid);
        gbar();
        // LSTM2: A = [h0_new | h1_old]
        gstage(32, wlds + 18432, b2p,
               h0p[q], 512, 16, h1p[p], 32, nullptr,
               cst + 512, h1p[q], gsc, half, nn, tid);
        gbar();
        // LSTM3
        gstage(32, wlds + 34816, b3p,
               h1p[q], 512, 16, h2p[p], 32, nullptr,
               cst + 1024, h2p[q], gsc, half, nn, tid);
        gbar();
        // attention (one row per CU)
        attstage(h2p[q], ENCB, ENCP, WaHT, Wa2, ba2v, ctx,
                 h2s, part, hp, sl, blk, tid);
        gbar();
        // head1: [h2 | ctx] -> hidden
        headstage<32, true>(packh1, bl1, h2p[q], ctx, 16,
                            hidden, nullptr, t, gsc, blk >> 5, blk & 31, tid);
        gbar();
        // head2: hidden -> out (96 blocks; off critical path, no barrier)
        if (blk < 96)
            headstage<16, false>(packh2, bl2, hidden, hidden, 16,
                                 nullptr, out, t, gsc, blk / 12, blk % 12, tid);
    }
}

// ---------------------------------------------------------------------------
extern "C" void kernel_launch(void* const* d_in, const int* in_sizes, int n_in,
                              void* d_out, int out_size, void* d_ws, size_t ws_size,
                              hipStream_t stream)
{
    const int*   act   = (const int*)d_in[0];
    const float* enc   = (const float*)d_in[1];
    const float* enc_h = (const float*)d_in[2];
    const float* enc_c = (const float*)d_in[3];
    const float* embW  = (const float*)d_in[4];
    const float* Wc    = (const float*)d_in[5];
    const float* bc    = (const float*)d_in[6];
    const float* Wih1  = (const float*)d_in[7];
    const float* Whh1  = (const float*)d_in[8];
    const float* bih1  = (const float*)d_in[9];
    const float* bhh1  = (const float*)d_in[10];
    const float* Wih2  = (const float*)d_in[11];
    const float* Whh2  = (const float*)d_in[12];
    const float* bih2  = (const float*)d_in[13];
    const float* bhh2  = (const float*)d_in[14];
    const float* Wih3  = (const float*)d_in[15];
    const float* Whh3  = (const float*)d_in[16];
    const float* bih3  = (const float*)d_in[17];
    const float* bhh3  = (const float*)d_in[18];
    const float* Wa1   = (const float*)d_in[19];
    const float* ba1   = (const float*)d_in[20];
    const float* Wa2   = (const float*)d_in[21];
    const float* ba2   = (const float*)d_in[22];
    const float* Wl1   = (const float*)d_in[23];
    const float* bl1   = (const float*)d_in[24];
    const float* Wl2   = (const float*)d_in[25];
    const float* bl2   = (const float*)d_in[26];
    float* out = (float*)d_out;

    char* cur = (char*)d_ws;
    auto alloc = [&](size_t bytes) {
        char* p = cur;
        cur += (bytes + 255) & ~(size_t)255;
        return p;
    };
    unsigned long long* bar = (unsigned long long*)alloc(256);
    short* pack1  = (short*)alloc((size_t)2048 * 1152 * 2);
    short* pack2  = (short*)alloc((size_t)2048 * 1024 * 2);
    short* pack3  = (short*)alloc((size_t)2048 * 1024 * 2);
    short* packh1 = (short*)alloc((size_t)512 * 1024 * 2);
    short* packh2 = (short*)alloc((size_t)192 * 512 * 2);
    // ENCB region doubles as W1f during prep (k_encb runs after k_pack1)
    short* ENCB   = (short*)alloc((size_t)BSZ * LLEN * 512 * 2);  // 16.8 MB
    float* W1f    = (float*)ENCB;                                  // 5.2 MB alias
    float* b1p    = (float*)alloc(2048 * 4);
    float* b2p    = (float*)alloc(2048 * 4);
    float* b3p    = (float*)alloc(2048 * 4);
    float* WaHT   = (float*)alloc(512 * HATT * 4);
    float* ENCP   = (float*)alloc((size_t)BSZ * LLEN * HATT * 4);
    short* ET     = (short*)alloc((size_t)TLEN * BSZ * EMBD * 2);
    const size_t SB = (size_t)BSZ * DH;
    short* h0a = (short*)alloc(SB * 2); short* h0b = (short*)alloc(SB * 2);
    short* h1a = (short*)alloc(SB * 2); short* h1b = (short*)alloc(SB * 2);
    short* h2a = (short*)alloc(SB * 2); short* h2b = (short*)alloc(SB * 2);
    short* ctx    = (short*)alloc(SB * 2);
    short* hidden = (short*)alloc(SB * 2);

    // ---- prep ----
    hipMemsetAsync(bar, 0, 256, stream);
    k_fold<<<dim3(32, 10), 256, 0, stream>>>(Wih1, Wc, W1f);
    k_pack1<<<1152, 256, 0, stream>>>(W1f, Whh1, pack1);
    k_encb<<<8192, 256, 0, stream>>>(enc, ENCB);      // overwrites W1f region
    k_pack23<<<1024, 256, 0, stream>>>(Wih2, Whh2, pack2);
    k_pack23<<<1024, 256, 0, stream>>>(Wih3, Whh3, pack3);
    k_packh1<<<256, 256, 0, stream>>>(Wl1, packh1);
    k_packh2<<<48, 256, 0, stream>>>(Wl2, packh2);
    k_bias<<<8, 256, 0, stream>>>(Wih1, bc, bih1, bhh1, bih2, bhh2, bih3, bhh3,
                                  b1p, b2p, b3p);
    k_tr<<<(HATT * 512 + 255) / 256, 256, 0, stream>>>(WaHT, Wa1 + 512, HATT, 512, 1024, HATT);
    k_encp<<<BSZ, 256, 0, stream>>>(enc, Wa1, ba1, ENCP);
    k_embed<<<(TLEN * BSZ * EMBD) / 256, 256, 0, stream>>>(act, embW, ET);
    k_init<<<512, 256, 0, stream>>>(enc_h, h0a, h1a, h2a, ctx);

    // ---- persistent recurrent megakernel ----
    k_mega<<<256, 512, 0, stream>>>(
        pack1, pack2, pack3, packh1, packh2,
        b1p, b2p, b3p, bl1, bl2,
        ET, ENCB, ENCP, WaHT, Wa2, ba2,
        enc_c,
        h0a, h0b, h1a, h1b, h2a, h2b,
        ctx, hidden, bar, out);
}

// Round 4
// 19889.532 us; speedup vs baseline: 1.8719x; 1.8719x over previous
//
#include <hip/hip_runtime.h>
#include <math.h>

constexpr int BSZ  = 256;
constexpr int TLEN = 128;
constexpr int LLEN = 64;
constexpr int DH   = 512;
constexpr int EMBD = 128;
constexpr int ACTN = 129;
constexpr int HATT = 20;

typedef short bf16x8 __attribute__((ext_vector_type(8)));
typedef float f32x4  __attribute__((ext_vector_type(4)));

__device__ __forceinline__ short f2bf(float f) {
    unsigned u = __builtin_bit_cast(unsigned, f);
    u += 0x7fffu + ((u >> 16) & 1u);
    return (short)(u >> 16);
}
__device__ __forceinline__ float bf2f(short s) {
    unsigned u = ((unsigned)(unsigned short)s) << 16;
    return __builtin_bit_cast(float, u);
}

// ---------------------------------------------------------------------------
// Prep: fold attn_combine into LSTM1  W1f[n][k] = sum_m Wih1[n][m]*Wc[m][k]
// ---------------------------------------------------------------------------
__launch_bounds__(256)
__global__ void k_fold(const float* __restrict__ Wih1, const float* __restrict__ Wc,
                       float* __restrict__ W1f)
{
    __shared__ float at[64][33];
    __shared__ float bt[32][65];
    int tid = threadIdx.x;
    int tx = tid & 15, ty = tid >> 4;
    int n0 = blockIdx.x * 64, k0 = blockIdx.y * 64;
    float acc[4][4] = {};
    for (int m0 = 0; m0 < 512; m0 += 32) {
        for (int i = 0; i < 8; ++i) {
            int idx = tid + 256 * i;
            int nl = idx >> 5, ml = idx & 31;
            at[nl][ml] = Wih1[(size_t)(n0 + nl) * 512 + m0 + ml];
        }
        for (int i = 0; i < 8; ++i) {
            int idx = tid + 256 * i;
            int ml = idx >> 6, kl = idx & 63;
            bt[ml][kl] = Wc[(size_t)(m0 + ml) * 640 + k0 + kl];
        }
        __syncthreads();
        for (int m = 0; m < 32; ++m) {
            #pragma unroll
            for (int i = 0; i < 4; ++i) {
                float av = at[ty * 4 + i][m];
                #pragma unroll
                for (int j = 0; j < 4; ++j)
                    acc[i][j] += av * bt[m][tx * 4 + j];
            }
        }
        __syncthreads();
    }
    for (int i = 0; i < 4; ++i)
        for (int j = 0; j < 4; ++j)
            W1f[(size_t)(n0 + ty * 4 + i) * 640 + (k0 + tx * 4 + j)] = acc[i][j];
}

// ---------------------------------------------------------------------------
// Weight packs (MFMA fragment order; LSTM packs gate-interleave columns)
// ---------------------------------------------------------------------------
__global__ void k_pack23(const float* __restrict__ Wih, const float* __restrict__ Whh,
                         short* __restrict__ pack)
{
    int idx = blockIdx.x * 256 + threadIdx.x;       // 262144
    int lane = idx & 63;
    int ks = (idx >> 6) & 31;
    int nn = idx >> 11;
    int np = nn * 16 + (lane & 15);
    int k  = ks * 32 + ((lane >> 4) << 3);
    int n  = (np & 3) * 512 + (np >> 2);
    const float* src = (k < 512) ? (Wih + (size_t)n * 512 + k)
                                 : (Whh + (size_t)n * 512 + (k - 512));
    short* dst = pack + (size_t)idx * 8;
    #pragma unroll
    for (int i = 0; i < 8; ++i) dst[i] = f2bf(src[i]);
}

__global__ void k_pack1(const float* __restrict__ W1f, const float* __restrict__ Whh1,
                        short* __restrict__ pack)
{
    int idx = blockIdx.x * 256 + threadIdx.x;       // 294912
    int lane = idx & 63;
    int tmp = idx >> 6;
    int ks = tmp % 36;
    int nn = tmp / 36;
    int np = nn * 16 + (lane & 15);
    int k  = ks * 32 + ((lane >> 4) << 3);
    int n  = (np & 3) * 512 + (np >> 2);
    const float* src = (k < 640) ? (W1f + (size_t)n * 640 + k)
                                 : (Whh1 + (size_t)n * 512 + (k - 640));
    short* dst = pack + (size_t)idx * 8;
    #pragma unroll
    for (int i = 0; i < 8; ++i) dst[i] = f2bf(src[i]);
}

__global__ void k_packh1(const float* __restrict__ Wl1, short* __restrict__ pack)
{
    int idx = blockIdx.x * 256 + threadIdx.x;       // 65536
    int lane = idx & 63;
    int ks = (idx >> 6) & 31;
    int nn = idx >> 11;                              // <32
    int np = nn * 16 + (lane & 15);                  // <512, no permute
    int k  = ks * 32 + ((lane >> 4) << 3);
    const float* src = Wl1 + (size_t)np * 1024 + k;
    short* dst = pack + (size_t)idx * 8;
    #pragma unroll
    for (int i = 0; i < 8; ++i) dst[i] = f2bf(src[i]);
}

__global__ void k_packh2(const float* __restrict__ Wl2, short* __restrict__ pack)
{
    int idx = blockIdx.x * 256 + threadIdx.x;       // 12288
    int lane = idx & 63;
    int ks = (idx >> 6) & 15;
    int nn = idx >> 10;                              // <12
    int np = nn * 16 + (lane & 15);                  // <192
    int k  = ks * 32 + ((lane >> 4) << 3);
    short* dst = pack + (size_t)idx * 8;
    if (np < ACTN) {
        const float* src = Wl2 + (size_t)np * 512 + k;
        #pragma unroll
        for (int i = 0; i < 8; ++i) dst[i] = f2bf(src[i]);
    } else {
        #pragma unroll
        for (int i = 0; i < 8; ++i) dst[i] = 0;
    }
}

// ---------------------------------------------------------------------------
// Permuted biases (b1p includes Wih1 @ bc)
// ---------------------------------------------------------------------------
__global__ void k_bias(const float* __restrict__ Wih1, const float* __restrict__ bc,
                       const float* bih1, const float* bhh1,
                       const float* bih2, const float* bhh2,
                       const float* bih3, const float* bhh3,
                       float* b1p, float* b2p, float* b3p)
{
    int cp = blockIdx.x * 256 + threadIdx.x;        // 2048
    int n = (cp & 3) * 512 + (cp >> 2);
    float s = bih1[n] + bhh1[n];
    for (int m = 0; m < 512; ++m) s += Wih1[(size_t)n * 512 + m] * bc[m];
    b1p[cp] = s;
    b2p[cp] = bih2[n] + bhh2[n];
    b3p[cp] = bih3[n] + bhh3[n];
}

__global__ void k_tr(float* __restrict__ dst, const float* __restrict__ src,
                     int R, int C, int sld, int dld)
{
    int idx = blockIdx.x * 256 + threadIdx.x;
    if (idx >= R * C) return;
    int c = idx / R, r = idx - c * R;
    dst[c * dld + r] = src[r * sld + c];
}

// ---------------------------------------------------------------------------
// ENCP[b][l][h] = enc[b][l][:] . Wa1[h][:512] + ba1[h]
// ---------------------------------------------------------------------------
__launch_bounds__(256)
__global__ void k_encp(const float* __restrict__ enc, const float* __restrict__ Wa1,
                       const float* __restrict__ ba1, float* __restrict__ ENCP)
{
    __shared__ float wa[HATT * 513];
    __shared__ float er[8][513];
    int b = blockIdx.x, tid = threadIdx.x;
    for (int idx = tid; idx < HATT * 512; idx += 256) {
        int h = idx >> 9, e = idx & 511;
        wa[h * 513 + e] = Wa1[h * 1024 + e];
    }
    __syncthreads();
    for (int c = 0; c < 8; ++c) {
        for (int i = 0; i < 16; ++i) {
            int idx = tid + 256 * i;
            int rr = idx >> 9, e = idx & 511;
            er[rr][e] = enc[((size_t)b * LLEN + c * 8 + rr) * 512 + e];
        }
        __syncthreads();
        if (tid < 8 * HATT) {
            int rr = tid & 7, h = tid >> 3;
            float s = 0.f;
            for (int e = 0; e < 512; ++e) s += er[rr][e] * wa[h * 513 + e];
            ENCP[((size_t)b * LLEN + c * 8 + rr) * HATT + h] = s + ba1[h];
        }
        __syncthreads();
    }
}

// ---------------------------------------------------------------------------
// ET[t][b][k] = bf16(embW[act[b][t-1]][k]); zeros at t=0
// ---------------------------------------------------------------------------
__global__ void k_embed(const int* __restrict__ act, const float* __restrict__ embW,
                        short* __restrict__ ET)
{
    int idx = blockIdx.x * 256 + threadIdx.x;       // 128*256*128
    int t = idx >> 15;
    int rem = idx & 32767;
    int b = rem >> 7, k = rem & 127;
    float v = 0.f;
    if (t > 0) v = embW[(size_t)act[b * TLEN + t - 1] * EMBD + k];
    ET[idx] = f2bf(v);
}

// enc -> bf16
__global__ void k_encb(const float* __restrict__ enc, short* __restrict__ ENCB)
{
    int i = blockIdx.x * 256 + threadIdx.x;
    float4 v = *(const float4*)&enc[(size_t)i * 4];
    short4 o;
    o.x = f2bf(v.x); o.y = f2bf(v.y); o.z = f2bf(v.z); o.w = f2bf(v.w);
    *(short4*)&ENCB[(size_t)i * 4] = o;
}

// h/ctx init
__global__ void k_init(const float* __restrict__ eh,
                       short* h0, short* h1, short* h2, short* ctx)
{
    int i = blockIdx.x * 256 + threadIdx.x;         // 131072
    short hb = f2bf(eh[i]);
    h0[i] = hb; h1[i] = hb; h2[i] = hb; ctx[i] = 0;
}

// ---------------------------------------------------------------------------
// Persistent megakernel: 256 blocks x 512 threads, 1 block/CU (LDS-forced).
// LSTM weight slices live in LDS for all 128 steps; c-state lives in LDS.
// Grid sync: monotonic-generation barrier. RELAXED polls (no per-poll cache
// invalidate); one release fetch_add per block; one acquire fence per wave.
// ---------------------------------------------------------------------------
__device__ __forceinline__ void gstage(
    int KS,
    const short* wl,                    // LDS weight slice
    const float* __restrict__ biasp,
    const short* __restrict__ a0, int ld0, int e1,   // ks <  e1 -> a0
    const short* __restrict__ a1, int e2,            // ks <  e2 -> a1 (ld 512)
    const short* __restrict__ a2,                    // else     -> a2 (ld 512)
    float* cst, short* __restrict__ hout,
    float* gsc, int half, int nn, int tid)
{
    const int wave = tid >> 6, lane = tid & 63;
    const int rlane = lane & 15, kq = lane >> 4;
    const int arow = half * 128 + wave * 16 + rlane;
    f32x4 acc0 = {}, acc1 = {};
    #pragma unroll 2
    for (int ks = 0; ks < KS; ks += 2) {
        {
            int k0 = ks * 32 + kq * 8;
            const short* ap;
            if (ks < e1)      ap = a0 + (size_t)arow * ld0 + k0;
            else if (ks < e2) ap = a1 + (size_t)arow * 512 + (k0 - e1 * 32);
            else              ap = a2 + (size_t)arow * 512 + (k0 - e2 * 32);
            bf16x8 af = *(const bf16x8*)ap;
            bf16x8 bf = *(const bf16x8*)&wl[(ks * 64 + lane) * 8];
            acc0 = __builtin_amdgcn_mfma_f32_16x16x32_bf16(af, bf, acc0, 0, 0, 0);
        }
        {
            int ks1 = ks + 1;
            int k0 = ks1 * 32 + kq * 8;
            const short* ap;
            if (ks1 < e1)      ap = a0 + (size_t)arow * ld0 + k0;
            else if (ks1 < e2) ap = a1 + (size_t)arow * 512 + (k0 - e1 * 32);
            else               ap = a2 + (size_t)arow * 512 + (k0 - e2 * 32);
            bf16x8 af = *(const bf16x8*)ap;
            bf16x8 bf = *(const bf16x8*)&wl[(ks1 * 64 + lane) * 8];
            acc1 = __builtin_amdgcn_mfma_f32_16x16x32_bf16(af, bf, acc1, 0, 0, 0);
        }
    }
    f32x4 acc = acc0 + acc1;
    float bp = biasp[nn * 16 + rlane];
    #pragma unroll
    for (int r = 0; r < 4; ++r)
        gsc[(wave * 16 + kq * 4 + r) * 17 + rlane] = acc[r] + bp;
    __syncthreads();
    {
        int row = tid >> 2, jl = tid & 3;           // tid < 512
        float gi = gsc[row * 17 + jl * 4 + 0];
        float gf = gsc[row * 17 + jl * 4 + 1];
        float gg = gsc[row * 17 + jl * 4 + 2];
        float go = gsc[row * 17 + jl * 4 + 3];
        float c  = cst[tid];
        float si = 1.f / (1.f + __expf(-gi));
        float sf = 1.f / (1.f + __expf(-gf));
        float so = 1.f / (1.f + __expf(-go));
        float cn = sf * c + si * tanhf(gg);
        float hn = so * tanhf(cn);
        cst[tid] = cn;
        hout[(size_t)(half * 128 + row) * 512 + nn * 4 + jl] = f2bf(hn);
    }
    __syncthreads();
}

template<int KSTEPS, bool RELU>
__device__ __forceinline__ void headstage(
    const short* __restrict__ packw, const float* __restrict__ biasv,
    const short* __restrict__ a0, const short* __restrict__ a1, int e1,
    short* __restrict__ hidden, float* __restrict__ out, int t,
    float* gsc, int mg, int ng, int tid)
{
    const int wave = tid >> 6, lane = tid & 63;
    const int rlane = lane & 15, kq = lane >> 4;
    constexpr int PER = KSTEPS / 8;
    f32x4 acc[2] = {};
    #pragma unroll
    for (int i = 0; i < PER; ++i) {
        int ks = wave * PER + i;
        int k0 = ks * 32 + kq * 8;
        const short* src; int kk;
        if (ks < e1) { src = a0; kk = k0; }
        else         { src = a1; kk = k0 - e1 * 32; }
        bf16x8 bfr = *(const bf16x8*)&packw[((size_t)(ng * KSTEPS + ks) * 64 + lane) * 8];
        bf16x8 af0 = *(const bf16x8*)(src + (size_t)(mg * 32 + rlane) * 512 + kk);
        bf16x8 af1 = *(const bf16x8*)(src + (size_t)(mg * 32 + 16 + rlane) * 512 + kk);
        acc[0] = __builtin_amdgcn_mfma_f32_16x16x32_bf16(af0, bfr, acc[0], 0, 0, 0);
        acc[1] = __builtin_amdgcn_mfma_f32_16x16x32_bf16(af1, bfr, acc[1], 0, 0, 0);
    }
    #pragma unroll
    for (int mf = 0; mf < 2; ++mf)
        #pragma unroll
        for (int r = 0; r < 4; ++r)
            gsc[wave * 512 + mf * 256 + (kq * 4 + r) * 16 + rlane] = acc[mf][r];
    __syncthreads();
    {
        int pos = tid;                               // < 512
        float s = 0.f;
        #pragma unroll
        for (int w = 0; w < 8; ++w) s += gsc[w * 512 + pos];
        int mf = pos >> 8, rr = (pos >> 4) & 15, cc = pos & 15;
        int row = mg * 32 + mf * 16 + rr, col = ng * 16 + cc;
        if (RELU) {
            hidden[(size_t)row * 512 + col] = f2bf(fmaxf(s + biasv[col], 0.f));
        } else if (col < ACTN) {
            out[((size_t)row * TLEN + t) * ACTN + col] = s + biasv[col];
        }
    }
    __syncthreads();
}

__device__ __forceinline__ void attstage(
    const short* __restrict__ h2q, const short* __restrict__ ENCB,
    const float* __restrict__ ENCP, const float* __restrict__ WaHT,
    const float* __restrict__ Wa2, const float* __restrict__ ba2v,
    short* __restrict__ ctx,
    float* h2s, float* part, float* hp, float* sl, int b, int tid)
{
    h2s[tid] = bf2f(h2q[(size_t)b * 512 + tid]);
    __syncthreads();
    if (tid < 8 * HATT) {
        int h = tid % HATT, sg = tid / HATT;
        float s = 0.f;
        for (int e = sg * 64; e < sg * 64 + 64; ++e) s += h2s[e] * WaHT[e * HATT + h];
        part[sg * HATT + h] = s;
    }
    __syncthreads();
    if (tid < HATT) {
        float s = 0.f;
        #pragma unroll
        for (int sg = 0; sg < 8; ++sg) s += part[sg * HATT + tid];
        hp[tid] = s;
    }
    __syncthreads();
    if (tid < LLEN) {
        float s = ba2v[0];
        const float* ep = ENCP + ((size_t)b * LLEN + tid) * HATT;
        #pragma unroll
        for (int h = 0; h < HATT; ++h)
            s += fmaxf(ep[h] + hp[h], 0.f) * Wa2[h];
        float v = tanhf(s);
        float m = v;
        for (int o = 32; o; o >>= 1) m = fmaxf(m, __shfl_xor(m, o));
        float e = __expf(v - m);
        float ss = e;
        for (int o = 32; o; o >>= 1) ss += __shfl_xor(ss, o);
        sl[tid] = e / ss;
    }
    __syncthreads();
    {
        float a = 0.f;
        const short* eb = ENCB + (size_t)b * LLEN * 512 + tid;
        #pragma unroll 8
        for (int l = 0; l < LLEN; ++l) a += sl[l] * bf2f(eb[l * 512]);
        ctx[(size_t)b * 512 + tid] = f2bf(a);
    }
    __syncthreads();
}

__launch_bounds__(512)
__global__ void k_mega(
    const short* __restrict__ pack1, const short* __restrict__ pack2,
    const short* __restrict__ pack3, const short* __restrict__ packh1,
    const short* __restrict__ packh2,
    const float* __restrict__ b1p, const float* __restrict__ b2p,
    const float* __restrict__ b3p, const float* __restrict__ bl1,
    const float* __restrict__ bl2,
    const short* __restrict__ ET, const short* __restrict__ ENCB,
    const float* __restrict__ ENCP, const float* __restrict__ WaHT,
    const float* __restrict__ Wa2, const float* __restrict__ ba2v,
    const float* __restrict__ enc_c,
    short* __restrict__ h0a, short* __restrict__ h0b,
    short* __restrict__ h1a, short* __restrict__ h1b,
    short* __restrict__ h2a, short* __restrict__ h2b,
    short* __restrict__ ctx, short* __restrict__ hidden,
    unsigned long long* __restrict__ bar,
    float* __restrict__ out)
{
    __shared__ short wlds[51200];        // 102.4 KB: W1|W2|W3 slices
    __shared__ float gsc[4096];          // 16 KB scratch
    __shared__ float cst[3 * 512];       // persistent c-state
    __shared__ float h2s[512];
    __shared__ float part[8 * HATT];
    __shared__ float hp[HATT];
    __shared__ float sl[LLEN];

    const int tid  = threadIdx.x;
    const int blk  = blockIdx.x;
    const int half = blk >> 7, nn = blk & 127;

    // --- park weight slices in LDS ---
    {
        const short* s1 = pack1 + (size_t)nn * 18432;
        const short* s2 = pack2 + (size_t)nn * 16384;
        const short* s3 = pack3 + (size_t)nn * 16384;
        for (int i = tid; i < 2304; i += 512)
            *(bf16x8*)&wlds[i * 8] = *(const bf16x8*)&s1[i * 8];
        for (int i = tid; i < 2048; i += 512) {
            *(bf16x8*)&wlds[18432 + i * 8] = *(const bf16x8*)&s2[i * 8];
            *(bf16x8*)&wlds[34816 + i * 8] = *(const bf16x8*)&s3[i * 8];
        }
    }
    // --- c-state init ---
    {
        int row = tid >> 2, jl = tid & 3;
        float cv = enc_c[(size_t)(half * 128 + row) * 512 + nn * 4 + jl];
        cst[tid] = cv; cst[512 + tid] = cv; cst[1024 + tid] = cv;
    }
    __syncthreads();

    int gen = 0;
    auto gbar = [&]() {
        ++gen;
        __syncthreads();                  // block writes complete (vmcnt drained)
        if (tid == 0) {
            // release: one wbl2 per block per barrier (dirty set is tiny)
            __hip_atomic_fetch_add(&bar[blk & 7], 1ull,
                                   __ATOMIC_RELEASE, __HIP_MEMORY_SCOPE_AGENT);
        }
        if (tid < 64) {
            const unsigned long long target = 256ull * (unsigned long long)gen;
            for (;;) {
                // RELAXED poll: coherent read, NO cache invalidate per iteration
                unsigned long long v = (tid < 8)
                    ? __hip_atomic_load(&bar[tid], __ATOMIC_RELAXED,
                                        __HIP_MEMORY_SCOPE_AGENT)
                    : 0ull;
                v += __shfl_xor(v, 1);
                v += __shfl_xor(v, 2);
                v += __shfl_xor(v, 4);
                if (__shfl(v, 0) >= target) break;
                __builtin_amdgcn_s_sleep(4);
            }
        }
        __syncthreads();
        // single acquire fence per wave: invalidate stale L1/L2 lines once
        __builtin_amdgcn_fence(__ATOMIC_ACQUIRE, "agent");
    };

    short* h0p[2] = { h0a, h0b };
    short* h1p[2] = { h1a, h1b };
    short* h2p[2] = { h2a, h2b };

    for (int t = 0; t < TLEN; ++t) {
        int p = t & 1, q = p ^ 1;
        // phase A: LSTM1  A = [ET(t) | ctx(t-1) | h0_old]
        gstage(36, wlds, b1p,
               ET + (size_t)t * BSZ * EMBD, 128, 4, ctx, 20, h0p[p],
               cst, h0p[q], gsc, half, nn, tid);
        gbar();                                   // bar1: h0(t), hidden(t-1)
        // phase B: LSTM2
        gstage(32, wlds + 18432, b2p,
               h0p[q], 512, 16, h1p[p], 32, nullptr,
               cst + 512, h1p[q], gsc, half, nn, tid);
        gbar();                                   // bar2: h1(t)
        // phase C: LSTM3
        gstage(32, wlds + 34816, b3p,
               h1p[q], 512, 16, h2p[p], 32, nullptr,
               cst + 1024, h2p[q], gsc, half, nn, tid);
        gbar();                                   // bar3: h2(t)
        // phase D: attention (1 row/CU) + head2(t-1) (96 blocks)
        attstage(h2p[q], ENCB, ENCP, WaHT, Wa2, ba2v, ctx,
                 h2s, part, hp, sl, blk, tid);
        if (t > 0 && blk < 96)
            headstage<16, false>(packh2, bl2, hidden, hidden, 16,
                                 nullptr, out, t - 1, gsc, blk / 12, blk % 12, tid);
        gbar();                                   // bar4: ctx(t)
        // phase E: head1 (flows into next step's LSTM1 without a barrier;
        // hidden(t) is synced for consumers at bar1 of step t+1)
        headstage<32, true>(packh1, bl1, h2p[q], ctx, 16,
                            hidden, nullptr, t, gsc, blk >> 5, blk & 31, tid);
    }
    // tail: head2 for t=127
    gbar();
    if (blk < 96)
        headstage<16, false>(packh2, bl2, hidden, hidden, 16,
                             nullptr, out, TLEN - 1, gsc, blk / 12, blk % 12, tid);
}

// ---------------------------------------------------------------------------
extern "C" void kernel_launch(void* const* d_in, const int* in_sizes, int n_in,
                              void* d_out, int out_size, void* d_ws, size_t ws_size,
                              hipStream_t stream)
{
    const int*   act   = (const int*)d_in[0];
    const float* enc   = (const float*)d_in[1];
    const float* enc_h = (const float*)d_in[2];
    const float* enc_c = (const float*)d_in[3];
    const float* embW  = (const float*)d_in[4];
    const float* Wc    = (const float*)d_in[5];
    const float* bc    = (const float*)d_in[6];
    const float* Wih1  = (const float*)d_in[7];
    const float* Whh1  = (const float*)d_in[8];
    const float* bih1  = (const float*)d_in[9];
    const float* bhh1  = (const float*)d_in[10];
    const float* Wih2  = (const float*)d_in[11];
    const float* Whh2  = (const float*)d_in[12];
    const float* bih2  = (const float*)d_in[13];
    const float* bhh2  = (const float*)d_in[14];
    const float* Wih3  = (const float*)d_in[15];
    const float* Whh3  = (const float*)d_in[16];
    const float* bih3  = (const float*)d_in[17];
    const float* bhh3  = (const float*)d_in[18];
    const float* Wa1   = (const float*)d_in[19];
    const float* ba1   = (const float*)d_in[20];
    const float* Wa2   = (const float*)d_in[21];
    const float* ba2   = (const float*)d_in[22];
    const float* Wl1   = (const float*)d_in[23];
    const float* bl1   = (const float*)d_in[24];
    const float* Wl2   = (const float*)d_in[25];
    const float* bl2   = (const float*)d_in[26];
    float* out = (float*)d_out;

    char* cur = (char*)d_ws;
    auto alloc = [&](size_t bytes) {
        char* p = cur;
        cur += (bytes + 255) & ~(size_t)255;
        return p;
    };
    unsigned long long* bar = (unsigned long long*)alloc(256);
    short* pack1  = (short*)alloc((size_t)2048 * 1152 * 2);
    short* pack2  = (short*)alloc((size_t)2048 * 1024 * 2);
    short* pack3  = (short*)alloc((size_t)2048 * 1024 * 2);
    short* packh1 = (short*)alloc((size_t)512 * 1024 * 2);
    short* packh2 = (short*)alloc((size_t)192 * 512 * 2);
    // ENCB region doubles as W1f during prep (k_encb runs after k_pack1)
    short* ENCB   = (short*)alloc((size_t)BSZ * LLEN * 512 * 2);  // 16.8 MB
    float* W1f    = (float*)ENCB;                                  // 5.2 MB alias
    float* b1p    = (float*)alloc(2048 * 4);
    float* b2p    = (float*)alloc(2048 * 4);
    float* b3p    = (float*)alloc(2048 * 4);
    float* WaHT   = (float*)alloc(512 * HATT * 4);
    float* ENCP   = (float*)alloc((size_t)BSZ * LLEN * HATT * 4);
    short* ET     = (short*)alloc((size_t)TLEN * BSZ * EMBD * 2);
    const size_t SB = (size_t)BSZ * DH;
    short* h0a = (short*)alloc(SB * 2); short* h0b = (short*)alloc(SB * 2);
    short* h1a = (short*)alloc(SB * 2); short* h1b = (short*)alloc(SB * 2);
    short* h2a = (short*)alloc(SB * 2); short* h2b = (short*)alloc(SB * 2);
    short* ctx    = (short*)alloc(SB * 2);
    short* hidden = (short*)alloc(SB * 2);

    // ---- prep ----
    hipMemsetAsync(bar, 0, 256, stream);
    k_fold<<<dim3(32, 10), 256, 0, stream>>>(Wih1, Wc, W1f);
    k_pack1<<<1152, 256, 0, stream>>>(W1f, Whh1, pack1);
    k_encb<<<8192, 256, 0, stream>>>(enc, ENCB);      // overwrites W1f region
    k_pack23<<<1024, 256, 0, stream>>>(Wih2, Whh2, pack2);
    k_pack23<<<1024, 256, 0, stream>>>(Wih3, Whh3, pack3);
    k_packh1<<<256, 256, 0, stream>>>(Wl1, packh1);
    k_packh2<<<48, 256, 0, stream>>>(Wl2, packh2);
    k_bias<<<8, 256, 0, stream>>>(Wih1, bc, bih1, bhh1, bih2, bhh2, bih3, bhh3,
                                  b1p, b2p, b3p);
    k_tr<<<(HATT * 512 + 255) / 256, 256, 0, stream>>>(WaHT, Wa1 + 512, HATT, 512, 1024, HATT);
    k_encp<<<BSZ, 256, 0, stream>>>(enc, Wa1, ba1, ENCP);
    k_embed<<<(TLEN * BSZ * EMBD) / 256, 256, 0, stream>>>(act, embW, ET);
    k_init<<<512, 256, 0, stream>>>(enc_h, h0a, h1a, h2a, ctx);

    // ---- persistent recurrent megakernel ----
    k_mega<<<256, 512, 0, stream>>>(
        pack1, pack2, pack3, packh1, packh2,
        b1p, b2p, b3p, bl1, bl2,
        ET, ENCB, ENCP, WaHT, Wa2, ba2,
        enc_c,
        h0a, h0b, h1a, h1b, h2a, h2b,
        ctx, hidden, bar, out);
}

// Round 5
// 19796.153 us; speedup vs baseline: 1.8807x; 1.0047x over previous
//
#include <hip/hip_runtime.h>
#include <math.h>

constexpr int BSZ  = 256;
constexpr int TLEN = 128;
constexpr int LLEN = 64;
constexpr int DH   = 512;
constexpr int EMBD = 128;
constexpr int ACTN = 129;
constexpr int HATT = 20;

typedef short bf16x8 __attribute__((ext_vector_type(8)));
typedef float f32x4  __attribute__((ext_vector_type(4)));

__device__ __forceinline__ short f2bf(float f) {
    unsigned u = __builtin_bit_cast(unsigned, f);
    u += 0x7fffu + ((u >> 16) & 1u);
    return (short)(u >> 16);
}
__device__ __forceinline__ float bf2f(short s) {
    unsigned u = ((unsigned)(unsigned short)s) << 16;
    return __builtin_bit_cast(float, u);
}

// ---------------------------------------------------------------------------
// Prep: fold attn_combine into LSTM1  W1f[n][k] = sum_m Wih1[n][m]*Wc[m][k]
// ---------------------------------------------------------------------------
__launch_bounds__(256)
__global__ void k_fold(const float* __restrict__ Wih1, const float* __restrict__ Wc,
                       float* __restrict__ W1f)
{
    __shared__ float at[64][33];
    __shared__ float bt[32][65];
    int tid = threadIdx.x;
    int tx = tid & 15, ty = tid >> 4;
    int n0 = blockIdx.x * 64, k0 = blockIdx.y * 64;
    float acc[4][4] = {};
    for (int m0 = 0; m0 < 512; m0 += 32) {
        for (int i = 0; i < 8; ++i) {
            int idx = tid + 256 * i;
            int nl = idx >> 5, ml = idx & 31;
            at[nl][ml] = Wih1[(size_t)(n0 + nl) * 512 + m0 + ml];
        }
        for (int i = 0; i < 8; ++i) {
            int idx = tid + 256 * i;
            int ml = idx >> 6, kl = idx & 63;
            bt[ml][kl] = Wc[(size_t)(m0 + ml) * 640 + k0 + kl];
        }
        __syncthreads();
        for (int m = 0; m < 32; ++m) {
            #pragma unroll
            for (int i = 0; i < 4; ++i) {
                float av = at[ty * 4 + i][m];
                #pragma unroll
                for (int j = 0; j < 4; ++j)
                    acc[i][j] += av * bt[m][tx * 4 + j];
            }
        }
        __syncthreads();
    }
    for (int i = 0; i < 4; ++i)
        for (int j = 0; j < 4; ++j)
            W1f[(size_t)(n0 + ty * 4 + i) * 640 + (k0 + tx * 4 + j)] = acc[i][j];
}

// ---------------------------------------------------------------------------
// Weight packs (MFMA fragment order; LSTM packs gate-interleave columns)
// ---------------------------------------------------------------------------
__global__ void k_pack23(const float* __restrict__ Wih, const float* __restrict__ Whh,
                         short* __restrict__ pack)
{
    int idx = blockIdx.x * 256 + threadIdx.x;       // 262144
    int lane = idx & 63;
    int ks = (idx >> 6) & 31;
    int nn = idx >> 11;
    int np = nn * 16 + (lane & 15);
    int k  = ks * 32 + ((lane >> 4) << 3);
    int n  = (np & 3) * 512 + (np >> 2);
    const float* src = (k < 512) ? (Wih + (size_t)n * 512 + k)
                                 : (Whh + (size_t)n * 512 + (k - 512));
    short* dst = pack + (size_t)idx * 8;
    #pragma unroll
    for (int i = 0; i < 8; ++i) dst[i] = f2bf(src[i]);
}

__global__ void k_pack1(const float* __restrict__ W1f, const float* __restrict__ Whh1,
                        short* __restrict__ pack)
{
    int idx = blockIdx.x * 256 + threadIdx.x;       // 294912
    int lane = idx & 63;
    int tmp = idx >> 6;
    int ks = tmp % 36;
    int nn = tmp / 36;
    int np = nn * 16 + (lane & 15);
    int k  = ks * 32 + ((lane >> 4) << 3);
    int n  = (np & 3) * 512 + (np >> 2);
    const float* src = (k < 640) ? (W1f + (size_t)n * 640 + k)
                                 : (Whh1 + (size_t)n * 512 + (k - 640));
    short* dst = pack + (size_t)idx * 8;
    #pragma unroll
    for (int i = 0; i < 8; ++i) dst[i] = f2bf(src[i]);
}

__global__ void k_packh1(const float* __restrict__ Wl1, short* __restrict__ pack)
{
    int idx = blockIdx.x * 256 + threadIdx.x;       // 65536
    int lane = idx & 63;
    int ks = (idx >> 6) & 31;
    int nn = idx >> 11;                              // <32
    int np = nn * 16 + (lane & 15);                  // <512, no permute
    int k  = ks * 32 + ((lane >> 4) << 3);
    const float* src = Wl1 + (size_t)np * 1024 + k;
    short* dst = pack + (size_t)idx * 8;
    #pragma unroll
    for (int i = 0; i < 8; ++i) dst[i] = f2bf(src[i]);
}

__global__ void k_packh2(const float* __restrict__ Wl2, short* __restrict__ pack)
{
    int idx = blockIdx.x * 256 + threadIdx.x;       // 12288
    int lane = idx & 63;
    int ks = (idx >> 6) & 15;
    int nn = idx >> 10;                              // <12
    int np = nn * 16 + (lane & 15);                  // <192
    int k  = ks * 32 + ((lane >> 4) << 3);
    short* dst = pack + (size_t)idx * 8;
    if (np < ACTN) {
        const float* src = Wl2 + (size_t)np * 512 + k;
        #pragma unroll
        for (int i = 0; i < 8; ++i) dst[i] = f2bf(src[i]);
    } else {
        #pragma unroll
        for (int i = 0; i < 8; ++i) dst[i] = 0;
    }
}

// ---------------------------------------------------------------------------
// Permuted biases (b1p includes Wih1 @ bc)
// ---------------------------------------------------------------------------
__global__ void k_bias(const float* __restrict__ Wih1, const float* __restrict__ bc,
                       const float* bih1, const float* bhh1,
                       const float* bih2, const float* bhh2,
                       const float* bih3, const float* bhh3,
                       float* b1p, float* b2p, float* b3p)
{
    int cp = blockIdx.x * 256 + threadIdx.x;        // 2048
    int n = (cp & 3) * 512 + (cp >> 2);
    float s = bih1[n] + bhh1[n];
    for (int m = 0; m < 512; ++m) s += Wih1[(size_t)n * 512 + m] * bc[m];
    b1p[cp] = s;
    b2p[cp] = bih2[n] + bhh2[n];
    b3p[cp] = bih3[n] + bhh3[n];
}

__global__ void k_tr(float* __restrict__ dst, const float* __restrict__ src,
                     int R, int C, int sld, int dld)
{
    int idx = blockIdx.x * 256 + threadIdx.x;
    if (idx >= R * C) return;
    int c = idx / R, r = idx - c * R;
    dst[c * dld + r] = src[r * sld + c];
}

// ---------------------------------------------------------------------------
// ENCP[b][l][h] = enc[b][l][:] . Wa1[h][:512] + ba1[h]
// ---------------------------------------------------------------------------
__launch_bounds__(256)
__global__ void k_encp(const float* __restrict__ enc, const float* __restrict__ Wa1,
                       const float* __restrict__ ba1, float* __restrict__ ENCP)
{
    __shared__ float wa[HATT * 513];
    __shared__ float er[8][513];
    int b = blockIdx.x, tid = threadIdx.x;
    for (int idx = tid; idx < HATT * 512; idx += 256) {
        int h = idx >> 9, e = idx & 511;
        wa[h * 513 + e] = Wa1[h * 1024 + e];
    }
    __syncthreads();
    for (int c = 0; c < 8; ++c) {
        for (int i = 0; i < 16; ++i) {
            int idx = tid + 256 * i;
            int rr = idx >> 9, e = idx & 511;
            er[rr][e] = enc[((size_t)b * LLEN + c * 8 + rr) * 512 + e];
        }
        __syncthreads();
        if (tid < 8 * HATT) {
            int rr = tid & 7, h = tid >> 3;
            float s = 0.f;
            for (int e = 0; e < 512; ++e) s += er[rr][e] * wa[h * 513 + e];
            ENCP[((size_t)b * LLEN + c * 8 + rr) * HATT + h] = s + ba1[h];
        }
        __syncthreads();
    }
}

// ---------------------------------------------------------------------------
// ET[t][b][k] = bf16(embW[act[b][t-1]][k]); zeros at t=0
// ---------------------------------------------------------------------------
__global__ void k_embed(const int* __restrict__ act, const float* __restrict__ embW,
                        short* __restrict__ ET)
{
    int idx = blockIdx.x * 256 + threadIdx.x;       // 128*256*128
    int t = idx >> 15;
    int rem = idx & 32767;
    int b = rem >> 7, k = rem & 127;
    float v = 0.f;
    if (t > 0) v = embW[(size_t)act[b * TLEN + t - 1] * EMBD + k];
    ET[idx] = f2bf(v);
}

// enc -> bf16
__global__ void k_encb(const float* __restrict__ enc, short* __restrict__ ENCB)
{
    int i = blockIdx.x * 256 + threadIdx.x;
    float4 v = *(const float4*)&enc[(size_t)i * 4];
    short4 o;
    o.x = f2bf(v.x); o.y = f2bf(v.y); o.z = f2bf(v.z); o.w = f2bf(v.w);
    *(short4*)&ENCB[(size_t)i * 4] = o;
}

// h/ctx init
__global__ void k_init(const float* __restrict__ eh,
                       short* h0, short* h1, short* h2, short* ctx)
{
    int i = blockIdx.x * 256 + threadIdx.x;         // 131072
    short hb = f2bf(eh[i]);
    h0[i] = hb; h1[i] = hb; h2[i] = hb; ctx[i] = 0;
}

// ---------------------------------------------------------------------------
// Persistent megakernel: 256 blocks x 512 threads, 1 block/CU (LDS-forced).
// LSTM weight slices live in LDS for all 128 steps; c-state lives in LDS.
// Grid sync: monotonic-generation barrier. RELAXED polls (no per-poll cache
// invalidate); one release fetch_add per block; one acquire fence per wave.
// ---------------------------------------------------------------------------
__device__ __forceinline__ void gstage(
    int KS,
    const short* wl,                    // LDS weight slice
    const float* __restrict__ biasp,
    const short* __restrict__ a0, int ld0, int e1,   // ks <  e1 -> a0
    const short* __restrict__ a1, int e2,            // ks <  e2 -> a1 (ld 512)
    const short* __restrict__ a2,                    // else     -> a2 (ld 512)
    float* cst, short* __restrict__ hout,
    float* gsc, int half, int nn, int tid)
{
    const int wave = tid >> 6, lane = tid & 63;
    const int rlane = lane & 15, kq = lane >> 4;
    const int arow = half * 128 + wave * 16 + rlane;
    f32x4 acc0 = {}, acc1 = {};
    #pragma unroll 2
    for (int ks = 0; ks < KS; ks += 2) {
        {
            int k0 = ks * 32 + kq * 8;
            const short* ap;
            if (ks < e1)      ap = a0 + (size_t)arow * ld0 + k0;
            else if (ks < e2) ap = a1 + (size_t)arow * 512 + (k0 - e1 * 32);
            else              ap = a2 + (size_t)arow * 512 + (k0 - e2 * 32);
            bf16x8 af = *(const bf16x8*)ap;
            bf16x8 bf = *(const bf16x8*)&wl[(ks * 64 + lane) * 8];
            acc0 = __builtin_amdgcn_mfma_f32_16x16x32_bf16(af, bf, acc0, 0, 0, 0);
        }
        {
            int ks1 = ks + 1;
            int k0 = ks1 * 32 + kq * 8;
            const short* ap;
            if (ks1 < e1)      ap = a0 + (size_t)arow * ld0 + k0;
            else if (ks1 < e2) ap = a1 + (size_t)arow * 512 + (k0 - e1 * 32);
            else               ap = a2 + (size_t)arow * 512 + (k0 - e2 * 32);
            bf16x8 af = *(const bf16x8*)ap;
            bf16x8 bf = *(const bf16x8*)&wl[(ks1 * 64 + lane) * 8];
            acc1 = __builtin_amdgcn_mfma_f32_16x16x32_bf16(af, bf, acc1, 0, 0, 0);
        }
    }
    f32x4 acc = acc0 + acc1;
    float bp = biasp[nn * 16 + rlane];
    #pragma unroll
    for (int r = 0; r < 4; ++r)
        gsc[(wave * 16 + kq * 4 + r) * 17 + rlane] = acc[r] + bp;
    __syncthreads();
    {
        int row = tid >> 2, jl = tid & 3;           // tid < 512
        float gi = gsc[row * 17 + jl * 4 + 0];
        float gf = gsc[row * 17 + jl * 4 + 1];
        float gg = gsc[row * 17 + jl * 4 + 2];
        float go = gsc[row * 17 + jl * 4 + 3];
        float c  = cst[tid];
        float si = 1.f / (1.f + __expf(-gi));
        float sf = 1.f / (1.f + __expf(-gf));
        float so = 1.f / (1.f + __expf(-go));
        float cn = sf * c + si * tanhf(gg);
        float hn = so * tanhf(cn);
        cst[tid] = cn;
        hout[(size_t)(half * 128 + row) * 512 + nn * 4 + jl] = f2bf(hn);
    }
    __syncthreads();
}

template<int KSTEPS, bool RELU>
__device__ __forceinline__ void headstage(
    const short* __restrict__ packw, const float* __restrict__ biasv,
    const short* __restrict__ a0, const short* __restrict__ a1, int e1,
    short* __restrict__ hidden, float* __restrict__ out, int t,
    float* gsc, int mg, int ng, int tid)
{
    const int wave = tid >> 6, lane = tid & 63;
    const int rlane = lane & 15, kq = lane >> 4;
    constexpr int PER = KSTEPS / 8;
    f32x4 acc[2] = {};
    #pragma unroll
    for (int i = 0; i < PER; ++i) {
        int ks = wave * PER + i;
        int k0 = ks * 32 + kq * 8;
        const short* src; int kk;
        if (ks < e1) { src = a0; kk = k0; }
        else         { src = a1; kk = k0 - e1 * 32; }
        bf16x8 bfr = *(const bf16x8*)&packw[((size_t)(ng * KSTEPS + ks) * 64 + lane) * 8];
        bf16x8 af0 = *(const bf16x8*)(src + (size_t)(mg * 32 + rlane) * 512 + kk);
        bf16x8 af1 = *(const bf16x8*)(src + (size_t)(mg * 32 + 16 + rlane) * 512 + kk);
        acc[0] = __builtin_amdgcn_mfma_f32_16x16x32_bf16(af0, bfr, acc[0], 0, 0, 0);
        acc[1] = __builtin_amdgcn_mfma_f32_16x16x32_bf16(af1, bfr, acc[1], 0, 0, 0);
    }
    #pragma unroll
    for (int mf = 0; mf < 2; ++mf)
        #pragma unroll
        for (int r = 0; r < 4; ++r)
            gsc[wave * 512 + mf * 256 + (kq * 4 + r) * 16 + rlane] = acc[mf][r];
    __syncthreads();
    {
        int pos = tid;                               // < 512
        float s = 0.f;
        #pragma unroll
        for (int w = 0; w < 8; ++w) s += gsc[w * 512 + pos];
        int mf = pos >> 8, rr = (pos >> 4) & 15, cc = pos & 15;
        int row = mg * 32 + mf * 16 + rr, col = ng * 16 + cc;
        if (RELU) {
            hidden[(size_t)row * 512 + col] = f2bf(fmaxf(s + biasv[col], 0.f));
        } else if (col < ACTN) {
            out[((size_t)row * TLEN + t) * ACTN + col] = s + biasv[col];
        }
    }
    __syncthreads();
}

__device__ __forceinline__ void attstage(
    const short* __restrict__ h2q, const short* __restrict__ ENCB,
    const float* __restrict__ ENCP, const float* __restrict__ WaHT,
    const float* __restrict__ Wa2, const float* __restrict__ ba2v,
    short* __restrict__ ctx,
    float* h2s, float* part, float* hp, float* sl, int b, int tid)
{
    h2s[tid] = bf2f(h2q[(size_t)b * 512 + tid]);
    __syncthreads();
    if (tid < 8 * HATT) {
        int h = tid % HATT, sg = tid / HATT;
        float s = 0.f;
        for (int e = sg * 64; e < sg * 64 + 64; ++e) s += h2s[e] * WaHT[e * HATT + h];
        part[sg * HATT + h] = s;
    }
    __syncthreads();
    if (tid < HATT) {
        float s = 0.f;
        #pragma unroll
        for (int sg = 0; sg < 8; ++sg) s += part[sg * HATT + tid];
        hp[tid] = s;
    }
    __syncthreads();
    if (tid < LLEN) {
        float s = ba2v[0];
        const float* ep = ENCP + ((size_t)b * LLEN + tid) * HATT;
        #pragma unroll
        for (int h = 0; h < HATT; ++h)
            s += fmaxf(ep[h] + hp[h], 0.f) * Wa2[h];
        float v = tanhf(s);
        float m = v;
        for (int o = 32; o; o >>= 1) m = fmaxf(m, __shfl_xor(m, o));
        float e = __expf(v - m);
        float ss = e;
        for (int o = 32; o; o >>= 1) ss += __shfl_xor(ss, o);
        sl[tid] = e / ss;
    }
    __syncthreads();
    {
        float a = 0.f;
        const short* eb = ENCB + (size_t)b * LLEN * 512 + tid;
        #pragma unroll 8
        for (int l = 0; l < LLEN; ++l) a += sl[l] * bf2f(eb[l * 512]);
        ctx[(size_t)b * 512 + tid] = f2bf(a);
    }
    __syncthreads();
}

__launch_bounds__(512)
__global__ void k_mega(
    const short* __restrict__ pack1, const short* __restrict__ pack2,
    const short* __restrict__ pack3, const short* __restrict__ packh1,
    const short* __restrict__ packh2,
    const float* __restrict__ b1p, const float* __restrict__ b2p,
    const float* __restrict__ b3p, const float* __restrict__ bl1,
    const float* __restrict__ bl2,
    const short* __restrict__ ET, const short* __restrict__ ENCB,
    const float* __restrict__ ENCP, const float* __restrict__ WaHT,
    const float* __restrict__ Wa2, const float* __restrict__ ba2v,
    const float* __restrict__ enc_c,
    short* __restrict__ h0a, short* __restrict__ h0b,
    short* __restrict__ h1a, short* __restrict__ h1b,
    short* __restrict__ h2a, short* __restrict__ h2b,
    short* __restrict__ ctx, short* __restrict__ hidden,
    unsigned long long* __restrict__ bar,
    float* __restrict__ out)
{
    __shared__ short wlds[51200];        // 102.4 KB: W1|W2|W3 slices
    __shared__ float gsc[4096];          // 16 KB scratch
    __shared__ float cst[3 * 512];       // persistent c-state
    __shared__ float h2s[512];
    __shared__ float part[8 * HATT];
    __shared__ float hp[HATT];
    __shared__ float sl[LLEN];

    const int tid  = threadIdx.x;
    const int blk  = blockIdx.x;
    const int half = blk >> 7, nn = blk & 127;

    // --- park weight slices in LDS ---
    {
        const short* s1 = pack1 + (size_t)nn * 18432;
        const short* s2 = pack2 + (size_t)nn * 16384;
        const short* s3 = pack3 + (size_t)nn * 16384;
        for (int i = tid; i < 2304; i += 512)
            *(bf16x8*)&wlds[i * 8] = *(const bf16x8*)&s1[i * 8];
        for (int i = tid; i < 2048; i += 512) {
            *(bf16x8*)&wlds[18432 + i * 8] = *(const bf16x8*)&s2[i * 8];
            *(bf16x8*)&wlds[34816 + i * 8] = *(const bf16x8*)&s3[i * 8];
        }
    }
    // --- c-state init ---
    {
        int row = tid >> 2, jl = tid & 3;
        float cv = enc_c[(size_t)(half * 128 + row) * 512 + nn * 4 + jl];
        cst[tid] = cv; cst[512 + tid] = cv; cst[1024 + tid] = cv;
    }
    __syncthreads();

    int gen = 0;
    auto gbar = [&]() {
        ++gen;
        __syncthreads();                  // block writes complete (vmcnt drained)
        if (tid == 0) {
            // release: one wbl2 per block per barrier (dirty set is tiny)
            __hip_atomic_fetch_add(&bar[blk & 7], 1ull,
                                   __ATOMIC_RELEASE, __HIP_MEMORY_SCOPE_AGENT);
        }
        if (tid < 64) {
            const unsigned long long target = 256ull * (unsigned long long)gen;
            for (;;) {
                // RELAXED poll: coherent read, NO cache invalidate per iteration
                unsigned long long v = (tid < 8)
                    ? __hip_atomic_load(&bar[tid], __ATOMIC_RELAXED,
                                        __HIP_MEMORY_SCOPE_AGENT)
                    : 0ull;
                v += __shfl_xor(v, 1);
                v += __shfl_xor(v, 2);
                v += __shfl_xor(v, 4);
                if (__shfl(v, 0) >= target) break;
                __builtin_amdgcn_s_sleep(4);
            }
        }
        __syncthreads();
        // single acquire fence per wave: invalidate stale L1/L2 lines once
        __builtin_amdgcn_fence(__ATOMIC_ACQUIRE, "agent");
    };

    short* h0p[2] = { h0a, h0b };
    short* h1p[2] = { h1a, h1b };
    short* h2p[2] = { h2a, h2b };

    for (int t = 0; t < TLEN; ++t) {
        int p = t & 1, q = p ^ 1;
        // phase A: LSTM1  A = [ET(t) | ctx(t-1) | h0_old]
        gstage(36, wlds, b1p,
               ET + (size_t)t * BSZ * EMBD, 128, 4, ctx, 20, h0p[p],
               cst, h0p[q], gsc, half, nn, tid);
        gbar();                                   // bar1: h0(t), hidden(t-1)
        // phase B: LSTM2
        gstage(32, wlds + 18432, b2p,
               h0p[q], 512, 16, h1p[p], 32, nullptr,
               cst + 512, h1p[q], gsc, half, nn, tid);
        gbar();                                   // bar2: h1(t)
        // phase C: LSTM3
        gstage(32, wlds + 34816, b3p,
               h1p[q], 512, 16, h2p[p], 32, nullptr,
               cst + 1024, h2p[q], gsc, half, nn, tid);
        gbar();                                   // bar3: h2(t)
        // phase D: attention (1 row/CU) + head2(t-1) (96 blocks)
        attstage(h2p[q], ENCB, ENCP, WaHT, Wa2, ba2v, ctx,
                 h2s, part, hp, sl, blk, tid);
        if (t > 0 && blk < 96)
            headstage<16, false>(packh2, bl2, hidden, hidden, 16,
                                 nullptr, out, t - 1, gsc, blk / 12, blk % 12, tid);
        gbar();                                   // bar4: ctx(t)
        // phase E: head1 (flows into next step's LSTM1 without a barrier;
        // hidden(t) is synced for consumers at bar1 of step t+1)
        headstage<32, true>(packh1, bl1, h2p[q], ctx, 16,
                            hidden, nullptr, t, gsc, blk >> 5, blk & 31, tid);
    }
    // tail: head2 for t=127
    gbar();
    if (blk < 96)
        headstage<16, false>(packh2, bl2, hidden, hidden, 16,
                             nullptr, out, TLEN - 1, gsc, blk / 12, blk % 12, tid);
}

// ---------------------------------------------------------------------------
extern "C" void kernel_launch(void* const* d_in, const int* in_sizes, int n_in,
                              void* d_out, int out_size, void* d_ws, size_t ws_size,
                              hipStream_t stream)
{
    const int*   act   = (const int*)d_in[0];
    const float* enc   = (const float*)d_in[1];
    const float* enc_h = (const float*)d_in[2];
    const float* enc_c = (const float*)d_in[3];
    const float* embW  = (const float*)d_in[4];
    const float* Wc    = (const float*)d_in[5];
    const float* bc    = (const float*)d_in[6];
    const float* Wih1  = (const float*)d_in[7];
    const float* Whh1  = (const float*)d_in[8];
    const float* bih1  = (const float*)d_in[9];
    const float* bhh1  = (const float*)d_in[10];
    const float* Wih2  = (const float*)d_in[11];
    const float* Whh2  = (const float*)d_in[12];
    const float* bih2  = (const float*)d_in[13];
    const float* bhh2  = (const float*)d_in[14];
    const float* Wih3  = (const float*)d_in[15];
    const float* Whh3  = (const float*)d_in[16];
    const float* bih3  = (const float*)d_in[17];
    const float* bhh3  = (const float*)d_in[18];
    const float* Wa1   = (const float*)d_in[19];
    const float* ba1   = (const float*)d_in[20];
    const float* Wa2   = (const float*)d_in[21];
    const float* ba2   = (const float*)d_in[22];
    const float* Wl1   = (const float*)d_in[23];
    const float* bl1   = (const float*)d_in[24];
    const float* Wl2   = (const float*)d_in[25];
    const float* bl2   = (const float*)d_in[26];
    float* out = (float*)d_out;

    char* cur = (char*)d_ws;
    auto alloc = [&](size_t bytes) {
        char* p = cur;
        cur += (bytes + 255) & ~(size_t)255;
        return p;
    };
    unsigned long long* bar = (unsigned long long*)alloc(256);
    short* pack1  = (short*)alloc((size_t)2048 * 1152 * 2);
    short* pack2  = (short*)alloc((size_t)2048 * 1024 * 2);
    short* pack3  = (short*)alloc((size_t)2048 * 1024 * 2);
    short* packh1 = (short*)alloc((size_t)512 * 1024 * 2);
    short* packh2 = (short*)alloc((size_t)192 * 512 * 2);
    // ENCB region doubles as W1f during prep (k_encb runs after k_pack1)
    short* ENCB   = (short*)alloc((size_t)BSZ * LLEN * 512 * 2);  // 16.8 MB
    float* W1f    = (float*)ENCB;                                  // 5.2 MB alias
    float* b1p    = (float*)alloc(2048 * 4);
    float* b2p    = (float*)alloc(2048 * 4);
    float* b3p    = (float*)alloc(2048 * 4);
    float* WaHT   = (float*)alloc(512 * HATT * 4);
    float* ENCP   = (float*)alloc((size_t)BSZ * LLEN * HATT * 4);
    short* ET     = (short*)alloc((size_t)TLEN * BSZ * EMBD * 2);
    const size_t SB = (size_t)BSZ * DH;
    short* h0a = (short*)alloc(SB * 2); short* h0b = (short*)alloc(SB * 2);
    short* h1a = (short*)alloc(SB * 2); short* h1b = (short*)alloc(SB * 2);
    short* h2a = (short*)alloc(SB * 2); short* h2b = (short*)alloc(SB * 2);
    short* ctx    = (short*)alloc(SB * 2);
    short* hidden = (short*)alloc(SB * 2);

    // ---- prep ----
    hipMemsetAsync(bar, 0, 256, stream);
    k_fold<<<dim3(32, 10), 256, 0, stream>>>(Wih1, Wc, W1f);
    k_pack1<<<1152, 256, 0, stream>>>(W1f, Whh1, pack1);
    k_encb<<<8192, 256, 0, stream>>>(enc, ENCB);      // overwrites W1f region
    k_pack23<<<1024, 256, 0, stream>>>(Wih2, Whh2, pack2);
    k_pack23<<<1024, 256, 0, stream>>>(Wih3, Whh3, pack3);
    k_packh1<<<256, 256, 0, stream>>>(Wl1, packh1);
    k_packh2<<<48, 256, 0, stream>>>(Wl2, packh2);
    k_bias<<<8, 256, 0, stream>>>(Wih1, bc, bih1, bhh1, bih2, bhh2, bih3, bhh3,
                                  b1p, b2p, b3p);
    k_tr<<<(HATT * 512 + 255) / 256, 256, 0, stream>>>(WaHT, Wa1 + 512, HATT, 512, 1024, HATT);
    k_encp<<<BSZ, 256, 0, stream>>>(enc, Wa1, ba1, ENCP);
    k_embed<<<(TLEN * BSZ * EMBD) / 256, 256, 0, stream>>>(act, embW, ET);
    k_init<<<512, 256, 0, stream>>>(enc_h, h0a, h1a, h2a, ctx);

    // ---- persistent recurrent megakernel ----
    k_mega<<<256, 512, 0, stream>>>(
        pack1, pack2, pack3, packh1, packh2,
        b1p, b2p, b3p, bl1, bl2,
        ET, ENCB, ENCP, WaHT, Wa2, ba2,
        enc_c,
        h0a, h0b, h1a, h1b, h2a, h2b,
        ctx, hidden, bar, out);
}

// Round 6
// 10295.526 us; speedup vs baseline: 3.6162x; 1.9228x over previous
//
#include <hip/hip_runtime.h>
#include <math.h>

constexpr int BSZ  = 256;
constexpr int TLEN = 128;
constexpr int LLEN = 64;
constexpr int DH   = 512;
constexpr int EMBD = 128;
constexpr int ACTN = 129;
constexpr int HATT = 20;

typedef short bf16x8 __attribute__((ext_vector_type(8)));
typedef float f32x4  __attribute__((ext_vector_type(4)));

__device__ __forceinline__ short f2bf(float f) {
    unsigned u = __builtin_bit_cast(unsigned, f);
    u += 0x7fffu + ((u >> 16) & 1u);
    return (short)(u >> 16);
}
__device__ __forceinline__ float bf2f(short s) {
    unsigned u = ((unsigned)(unsigned short)s) << 16;
    return __builtin_bit_cast(float, u);
}

// ---------------------------------------------------------------------------
// Prep kernels (unchanged from round 5, proven correct)
// ---------------------------------------------------------------------------
__launch_bounds__(256)
__global__ void k_fold(const float* __restrict__ Wih1, const float* __restrict__ Wc,
                       float* __restrict__ W1f)
{
    __shared__ float at[64][33];
    __shared__ float bt[32][65];
    int tid = threadIdx.x;
    int tx = tid & 15, ty = tid >> 4;
    int n0 = blockIdx.x * 64, k0 = blockIdx.y * 64;
    float acc[4][4] = {};
    for (int m0 = 0; m0 < 512; m0 += 32) {
        for (int i = 0; i < 8; ++i) {
            int idx = tid + 256 * i;
            int nl = idx >> 5, ml = idx & 31;
            at[nl][ml] = Wih1[(size_t)(n0 + nl) * 512 + m0 + ml];
        }
        for (int i = 0; i < 8; ++i) {
            int idx = tid + 256 * i;
            int ml = idx >> 6, kl = idx & 63;
            bt[ml][kl] = Wc[(size_t)(m0 + ml) * 640 + k0 + kl];
        }
        __syncthreads();
        for (int m = 0; m < 32; ++m) {
            #pragma unroll
            for (int i = 0; i < 4; ++i) {
                float av = at[ty * 4 + i][m];
                #pragma unroll
                for (int j = 0; j < 4; ++j)
                    acc[i][j] += av * bt[m][tx * 4 + j];
            }
        }
        __syncthreads();
    }
    for (int i = 0; i < 4; ++i)
        for (int j = 0; j < 4; ++j)
            W1f[(size_t)(n0 + ty * 4 + i) * 640 + (k0 + tx * 4 + j)] = acc[i][j];
}

__global__ void k_pack23(const float* __restrict__ Wih, const float* __restrict__ Whh,
                         short* __restrict__ pack)
{
    int idx = blockIdx.x * 256 + threadIdx.x;       // 262144
    int lane = idx & 63;
    int ks = (idx >> 6) & 31;
    int nn = idx >> 11;
    int np = nn * 16 + (lane & 15);
    int k  = ks * 32 + ((lane >> 4) << 3);
    int n  = (np & 3) * 512 + (np >> 2);
    const float* src = (k < 512) ? (Wih + (size_t)n * 512 + k)
                                 : (Whh + (size_t)n * 512 + (k - 512));
    short* dst = pack + (size_t)idx * 8;
    #pragma unroll
    for (int i = 0; i < 8; ++i) dst[i] = f2bf(src[i]);
}

__global__ void k_pack1(const float* __restrict__ W1f, const float* __restrict__ Whh1,
                        short* __restrict__ pack)
{
    int idx = blockIdx.x * 256 + threadIdx.x;       // 294912
    int lane = idx & 63;
    int tmp = idx >> 6;
    int ks = tmp % 36;
    int nn = tmp / 36;
    int np = nn * 16 + (lane & 15);
    int k  = ks * 32 + ((lane >> 4) << 3);
    int n  = (np & 3) * 512 + (np >> 2);
    const float* src = (k < 640) ? (W1f + (size_t)n * 640 + k)
                                 : (Whh1 + (size_t)n * 512 + (k - 640));
    short* dst = pack + (size_t)idx * 8;
    #pragma unroll
    for (int i = 0; i < 8; ++i) dst[i] = f2bf(src[i]);
}

__global__ void k_packh1(const float* __restrict__ Wl1, short* __restrict__ pack)
{
    int idx = blockIdx.x * 256 + threadIdx.x;       // 65536
    int lane = idx & 63;
    int ks = (idx >> 6) & 31;
    int nn = idx >> 11;                              // <32
    int np = nn * 16 + (lane & 15);
    int k  = ks * 32 + ((lane >> 4) << 3);
    const float* src = Wl1 + (size_t)np * 1024 + k;
    short* dst = pack + (size_t)idx * 8;
    #pragma unroll
    for (int i = 0; i < 8; ++i) dst[i] = f2bf(src[i]);
}

__global__ void k_packh2(const float* __restrict__ Wl2, short* __restrict__ pack)
{
    int idx = blockIdx.x * 256 + threadIdx.x;       // 12288
    int lane = idx & 63;
    int ks = (idx >> 6) & 15;
    int nn = idx >> 10;                              // <12
    int np = nn * 16 + (lane & 15);
    int k  = ks * 32 + ((lane >> 4) << 3);
    short* dst = pack + (size_t)idx * 8;
    if (np < ACTN) {
        const float* src = Wl2 + (size_t)np * 512 + k;
        #pragma unroll
        for (int i = 0; i < 8; ++i) dst[i] = f2bf(src[i]);
    } else {
        #pragma unroll
        for (int i = 0; i < 8; ++i) dst[i] = 0;
    }
}

__global__ void k_bias(const float* __restrict__ Wih1, const float* __restrict__ bc,
                       const float* bih1, const float* bhh1,
                       const float* bih2, const float* bhh2,
                       const float* bih3, const float* bhh3,
                       float* b1p, float* b2p, float* b3p)
{
    int cp = blockIdx.x * 256 + threadIdx.x;        // 2048
    int n = (cp & 3) * 512 + (cp >> 2);
    float s = bih1[n] + bhh1[n];
    for (int m = 0; m < 512; ++m) s += Wih1[(size_t)n * 512 + m] * bc[m];
    b1p[cp] = s;
    b2p[cp] = bih2[n] + bhh2[n];
    b3p[cp] = bih3[n] + bhh3[n];
}

__global__ void k_tr(float* __restrict__ dst, const float* __restrict__ src,
                     int R, int C, int sld, int dld)
{
    int idx = blockIdx.x * 256 + threadIdx.x;
    if (idx >= R * C) return;
    int c = idx / R, r = idx - c * R;
    dst[c * dld + r] = src[r * sld + c];
}

__launch_bounds__(256)
__global__ void k_encp(const float* __restrict__ enc, const float* __restrict__ Wa1,
                       const float* __restrict__ ba1, float* __restrict__ ENCP)
{
    __shared__ float wa[HATT * 513];
    __shared__ float er[8][513];
    int b = blockIdx.x, tid = threadIdx.x;
    for (int idx = tid; idx < HATT * 512; idx += 256) {
        int h = idx >> 9, e = idx & 511;
        wa[h * 513 + e] = Wa1[h * 1024 + e];
    }
    __syncthreads();
    for (int c = 0; c < 8; ++c) {
        for (int i = 0; i < 16; ++i) {
            int idx = tid + 256 * i;
            int rr = idx >> 9, e = idx & 511;
            er[rr][e] = enc[((size_t)b * LLEN + c * 8 + rr) * 512 + e];
        }
        __syncthreads();
        if (tid < 8 * HATT) {
            int rr = tid & 7, h = tid >> 3;
            float s = 0.f;
            for (int e = 0; e < 512; ++e) s += er[rr][e] * wa[h * 513 + e];
            ENCP[((size_t)b * LLEN + c * 8 + rr) * HATT + h] = s + ba1[h];
        }
        __syncthreads();
    }
}

__global__ void k_embed(const int* __restrict__ act, const float* __restrict__ embW,
                        short* __restrict__ ET)
{
    int idx = blockIdx.x * 256 + threadIdx.x;       // 128*256*128
    int t = idx >> 15;
    int rem = idx & 32767;
    int b = rem >> 7, k = rem & 127;
    float v = 0.f;
    if (t > 0) v = embW[(size_t)act[b * TLEN + t - 1] * EMBD + k];
    ET[idx] = f2bf(v);
}

__global__ void k_encb(const float* __restrict__ enc, short* __restrict__ ENCB)
{
    int i = blockIdx.x * 256 + threadIdx.x;
    float4 v = *(const float4*)&enc[(size_t)i * 4];
    short4 o;
    o.x = f2bf(v.x); o.y = f2bf(v.y); o.z = f2bf(v.z); o.w = f2bf(v.w);
    *(short4*)&ENCB[(size_t)i * 4] = o;
}

__global__ void k_init(const float* __restrict__ eh,
                       short* h0, short* h1, short* h2, short* ctx)
{
    int i = blockIdx.x * 256 + threadIdx.x;         // 131072
    short hb = f2bf(eh[i]);
    h0[i] = hb; h1[i] = hb; h2[i] = hb; ctx[i] = 0;
}

// ---------------------------------------------------------------------------
// sc0 (L1-bypass, L2-hit) state loads — inline asm, waitcnt bundled so the
// compiler never consumes results early; sched_barrier pins ordering (#18).
// ---------------------------------------------------------------------------
__device__ __forceinline__ void load_a8(const short* base,
    bf16x8& a0, bf16x8& a1, bf16x8& a2, bf16x8& a3,
    bf16x8& a4, bf16x8& a5, bf16x8& a6, bf16x8& a7)
{
    asm volatile(
        "global_load_dwordx4 %0, %8, off sc0\n\t"
        "global_load_dwordx4 %1, %8, off offset:64 sc0\n\t"
        "global_load_dwordx4 %2, %8, off offset:128 sc0\n\t"
        "global_load_dwordx4 %3, %8, off offset:192 sc0\n\t"
        "global_load_dwordx4 %4, %8, off offset:256 sc0\n\t"
        "global_load_dwordx4 %5, %8, off offset:320 sc0\n\t"
        "global_load_dwordx4 %6, %8, off offset:384 sc0\n\t"
        "global_load_dwordx4 %7, %8, off offset:448 sc0\n\t"
        "s_waitcnt vmcnt(0)"
        : "=&v"(a0), "=&v"(a1), "=&v"(a2), "=&v"(a3),
          "=&v"(a4), "=&v"(a5), "=&v"(a6), "=&v"(a7)
        : "v"(base) : "memory");
    __builtin_amdgcn_sched_barrier(0);
}

__device__ __forceinline__ void load_a4(const short* base,
    bf16x8& a0, bf16x8& a1, bf16x8& a2, bf16x8& a3)
{
    asm volatile(
        "global_load_dwordx4 %0, %4, off sc0\n\t"
        "global_load_dwordx4 %1, %4, off offset:64 sc0\n\t"
        "global_load_dwordx4 %2, %4, off offset:128 sc0\n\t"
        "global_load_dwordx4 %3, %4, off offset:192 sc0\n\t"
        "s_waitcnt vmcnt(0)"
        : "=&v"(a0), "=&v"(a1), "=&v"(a2), "=&v"(a3)
        : "v"(base) : "memory");
    __builtin_amdgcn_sched_barrier(0);
}

__device__ __forceinline__ bf16x8 load_a1(const short* p)
{
    bf16x8 r;
    asm volatile("global_load_dwordx4 %0, %1, off sc0\n\t"
                 "s_waitcnt vmcnt(0)"
                 : "=&v"(r) : "v"(p) : "memory");
    __builtin_amdgcn_sched_barrier(0);
    return r;
}

// ---------------------------------------------------------------------------
// LSTM stage: M=32 (XCD's batch rows), N=64 gate-cols (this block's slice),
// K = KS*32. Waves: 2m x 4n. B from LDS (W2) or streamed global (nt).
// State A-frags via sc0 chunks. Epilogue: fused cell update, h -> plain store.
// ---------------------------------------------------------------------------
template<int KS, int KSET, bool WLDS>
__device__ __forceinline__ void lstm_stage(
    const short* __restrict__ packW, const short* wlds,
    const float* __restrict__ biasp, const short* __restrict__ ET_t,
    const short* __restrict__ s1, const short* __restrict__ s2,
    float* cstS, short* __restrict__ hout, float* gsc,
    int brow0, int lr, int tid)
{
    const int wave = tid >> 6, lane = tid & 63;
    const int wm = wave >> 2, wn = wave & 3;
    const int rlane = lane & 15, kq = lane >> 4;
    const int arow = brow0 + wm * 16 + rlane;
    const int ct = lr * 4 + wn;
    f32x4 acc = {};

    if constexpr (KSET > 0) {
        const short* ap = ET_t + (size_t)arow * EMBD + kq * 8;
        const short* bp = packW + ((size_t)(ct * KS) * 64 + lane) * 8;
        #pragma unroll
        for (int ks = 0; ks < KSET; ++ks) {
            bf16x8 bf = __builtin_nontemporal_load((const bf16x8*)(bp + ks * 512));
            bf16x8 af = *(const bf16x8*)(ap + ks * 32);
            acc = __builtin_amdgcn_mfma_f32_16x16x32_bf16(af, bf, acc, 0, 0, 0);
        }
    }
    #pragma unroll
    for (int c = 0; c < (KS - KSET) / 8; ++c) {
        const int kss = c * 8;
        const short* src = (kss < 16) ? s1 : s2;
        const int krel = kss & 15;
        const short* abase = src + (size_t)arow * 512 + krel * 32 + kq * 8;
        bf16x8 b0, b1, b2, b3, b4, b5, b6, b7;
        if constexpr (WLDS) {
            const short* wb = wlds + ((wn * 32 + kss) * 64 + lane) * 8;
            b0 = *(const bf16x8*)(wb + 0 * 512);  b1 = *(const bf16x8*)(wb + 1 * 512);
            b2 = *(const bf16x8*)(wb + 2 * 512);  b3 = *(const bf16x8*)(wb + 3 * 512);
            b4 = *(const bf16x8*)(wb + 4 * 512);  b5 = *(const bf16x8*)(wb + 5 * 512);
            b6 = *(const bf16x8*)(wb + 6 * 512);  b7 = *(const bf16x8*)(wb + 7 * 512);
        } else {
            const short* wb = packW + ((size_t)(ct * KS + KSET + kss) * 64 + lane) * 8;
            b0 = __builtin_nontemporal_load((const bf16x8*)(wb + 0 * 512));
            b1 = __builtin_nontemporal_load((const bf16x8*)(wb + 1 * 512));
            b2 = __builtin_nontemporal_load((const bf16x8*)(wb + 2 * 512));
            b3 = __builtin_nontemporal_load((const bf16x8*)(wb + 3 * 512));
            b4 = __builtin_nontemporal_load((const bf16x8*)(wb + 4 * 512));
            b5 = __builtin_nontemporal_load((const bf16x8*)(wb + 5 * 512));
            b6 = __builtin_nontemporal_load((const bf16x8*)(wb + 6 * 512));
            b7 = __builtin_nontemporal_load((const bf16x8*)(wb + 7 * 512));
        }
        bf16x8 a0, a1, a2, a3, a4, a5, a6, a7;
        load_a8(abase, a0, a1, a2, a3, a4, a5, a6, a7);
        acc = __builtin_amdgcn_mfma_f32_16x16x32_bf16(a0, b0, acc, 0, 0, 0);
        acc = __builtin_amdgcn_mfma_f32_16x16x32_bf16(a1, b1, acc, 0, 0, 0);
        acc = __builtin_amdgcn_mfma_f32_16x16x32_bf16(a2, b2, acc, 0, 0, 0);
        acc = __builtin_amdgcn_mfma_f32_16x16x32_bf16(a3, b3, acc, 0, 0, 0);
        acc = __builtin_amdgcn_mfma_f32_16x16x32_bf16(a4, b4, acc, 0, 0, 0);
        acc = __builtin_amdgcn_mfma_f32_16x16x32_bf16(a5, b5, acc, 0, 0, 0);
        acc = __builtin_amdgcn_mfma_f32_16x16x32_bf16(a6, b6, acc, 0, 0, 0);
        acc = __builtin_amdgcn_mfma_f32_16x16x32_bf16(a7, b7, acc, 0, 0, 0);
    }
    #pragma unroll
    for (int r = 0; r < 4; ++r)
        gsc[(wm * 16 + kq * 4 + r) * 68 + wn * 16 + rlane] = acc[r];
    __syncthreads();
    {
        int row = tid >> 4, j = tid & 15;
        float4 bv = *(const float4*)&biasp[(lr * 16 + j) * 4];
        float gi = gsc[row * 68 + j * 4 + 0] + bv.x;
        float gf = gsc[row * 68 + j * 4 + 1] + bv.y;
        float gg = gsc[row * 68 + j * 4 + 2] + bv.z;
        float go = gsc[row * 68 + j * 4 + 3] + bv.w;
        float c0 = cstS[tid];
        float si = 1.f / (1.f + __expf(-gi));
        float sf = 1.f / (1.f + __expf(-gf));
        float so = 1.f / (1.f + __expf(-go));
        float cn = sf * c0 + si * tanhf(gg);
        cstS[tid] = cn;
        hout[(size_t)(brow0 + row) * 512 + lr * 16 + j] = f2bf(so * tanhf(cn));
    }
}

// ---------------------------------------------------------------------------
// head1: M=32, block's 16 cols of 512, K=1024 split 4-way over waves + reduce.
// ---------------------------------------------------------------------------
__device__ __forceinline__ void head1_stage(
    const short* __restrict__ ph1, const float* __restrict__ bl1,
    const short* __restrict__ h2q, const short* __restrict__ ctx,
    short* __restrict__ hidden, float* gsc, int brow0, int lr, int tid)
{
    const int wave = tid >> 6, lane = tid & 63;
    const int wm = wave & 1, kq2 = wave >> 1;        // kq2: 0..3
    const int rlane = lane & 15, kq = lane >> 4;
    const int arow = brow0 + wm * 16 + rlane;
    const short* src = (kq2 < 2) ? h2q : ctx;
    const int krel = (kq2 & 1) * 8;
    const short* abase = src + (size_t)arow * 512 + krel * 32 + kq * 8;
    const short* wb = ph1 + ((size_t)(lr * 32 + kq2 * 8) * 64 + lane) * 8;
    bf16x8 b0 = __builtin_nontemporal_load((const bf16x8*)(wb + 0 * 512));
    bf16x8 b1 = __builtin_nontemporal_load((const bf16x8*)(wb + 1 * 512));
    bf16x8 b2 = __builtin_nontemporal_load((const bf16x8*)(wb + 2 * 512));
    bf16x8 b3 = __builtin_nontemporal_load((const bf16x8*)(wb + 3 * 512));
    bf16x8 b4 = __builtin_nontemporal_load((const bf16x8*)(wb + 4 * 512));
    bf16x8 b5 = __builtin_nontemporal_load((const bf16x8*)(wb + 5 * 512));
    bf16x8 b6 = __builtin_nontemporal_load((const bf16x8*)(wb + 6 * 512));
    bf16x8 b7 = __builtin_nontemporal_load((const bf16x8*)(wb + 7 * 512));
    bf16x8 a0, a1, a2, a3, a4, a5, a6, a7;
    load_a8(abase, a0, a1, a2, a3, a4, a5, a6, a7);
    f32x4 acc = {};
    acc = __builtin_amdgcn_mfma_f32_16x16x32_bf16(a0, b0, acc, 0, 0, 0);
    acc = __builtin_amdgcn_mfma_f32_16x16x32_bf16(a1, b1, acc, 0, 0, 0);
    acc = __builtin_amdgcn_mfma_f32_16x16x32_bf16(a2, b2, acc, 0, 0, 0);
    acc = __builtin_amdgcn_mfma_f32_16x16x32_bf16(a3, b3, acc, 0, 0, 0);
    acc = __builtin_amdgcn_mfma_f32_16x16x32_bf16(a4, b4, acc, 0, 0, 0);
    acc = __builtin_amdgcn_mfma_f32_16x16x32_bf16(a5, b5, acc, 0, 0, 0);
    acc = __builtin_amdgcn_mfma_f32_16x16x32_bf16(a6, b6, acc, 0, 0, 0);
    acc = __builtin_amdgcn_mfma_f32_16x16x32_bf16(a7, b7, acc, 0, 0, 0);
    #pragma unroll
    for (int r = 0; r < 4; ++r)
        gsc[(kq2 * 2 + wm) * 256 + (kq * 4 + r) * 16 + rlane] = acc[r];
    __syncthreads();
    {
        float s = 0.f;
        #pragma unroll
        for (int k = 0; k < 4; ++k) s += gsc[(k * 2 + (tid >> 8)) * 256 + (tid & 255)];
        int row = (tid >> 8) * 16 + ((tid >> 4) & 15);
        int col = lr * 16 + (tid & 15);
        hidden[(size_t)(brow0 + row) * 512 + col] = f2bf(fmaxf(s + bl1[col], 0.f));
    }
    __syncthreads();   // gsc reused by next step's LSTM1 without a grid barrier
}

// ---------------------------------------------------------------------------
// head2 (blocks lr 9..17): M=32, n-tile of 16 (cols nt*16..), K=512.
// ---------------------------------------------------------------------------
__device__ __forceinline__ void head2_stage(
    const short* __restrict__ ph2, const float* __restrict__ bl2,
    const short* __restrict__ hidden, float* __restrict__ out, int t,
    float* gsc, int brow0, int nt, int tid)
{
    const int wave = tid >> 6, lane = tid & 63;
    const int wm = wave & 1, kq4 = wave >> 1;        // kq4: 0..3
    const int rlane = lane & 15, kq = lane >> 4;
    const int arow = brow0 + wm * 16 + rlane;
    const short* abase = hidden + (size_t)arow * 512 + kq4 * 128 + kq * 8;
    const short* wb = ph2 + ((size_t)(nt * 16 + kq4 * 4) * 64 + lane) * 8;
    bf16x8 b0 = __builtin_nontemporal_load((const bf16x8*)(wb + 0 * 512));
    bf16x8 b1 = __builtin_nontemporal_load((const bf16x8*)(wb + 1 * 512));
    bf16x8 b2 = __builtin_nontemporal_load((const bf16x8*)(wb + 2 * 512));
    bf16x8 b3 = __builtin_nontemporal_load((const bf16x8*)(wb + 3 * 512));
    bf16x8 a0, a1, a2, a3;
    load_a4(abase, a0, a1, a2, a3);
    f32x4 acc = {};
    acc = __builtin_amdgcn_mfma_f32_16x16x32_bf16(a0, b0, acc, 0, 0, 0);
    acc = __builtin_amdgcn_mfma_f32_16x16x32_bf16(a1, b1, acc, 0, 0, 0);
    acc = __builtin_amdgcn_mfma_f32_16x16x32_bf16(a2, b2, acc, 0, 0, 0);
    acc = __builtin_amdgcn_mfma_f32_16x16x32_bf16(a3, b3, acc, 0, 0, 0);
    #pragma unroll
    for (int r = 0; r < 4; ++r)
        gsc[(kq4 * 2 + wm) * 256 + (kq * 4 + r) * 16 + rlane] = acc[r];
    __syncthreads();
    {
        float s = 0.f;
        #pragma unroll
        for (int k = 0; k < 4; ++k) s += gsc[(k * 2 + (tid >> 8)) * 256 + (tid & 255)];
        int row = (tid >> 8) * 16 + ((tid >> 4) & 15);
        int col = nt * 16 + (tid & 15);
        if (col < ACTN)
            out[((size_t)(brow0 + row) * TLEN + t) * ACTN + col] = s + bl2[col];
    }
}

// ---------------------------------------------------------------------------
// attention: one batch row per block (b = brow0 + lr)
// ---------------------------------------------------------------------------
__device__ __forceinline__ void attn_stage(
    const short* __restrict__ h2q, const short* __restrict__ ENCB,
    const float* __restrict__ ENCP, const float* __restrict__ WaHT,
    const float* __restrict__ Wa2, const float* __restrict__ ba2v,
    short* __restrict__ ctx,
    float* h2s, float* part, float* hp, float* sl, int b, int tid)
{
    if (tid < 64) {
        bf16x8 v = load_a1(h2q + (size_t)b * 512 + tid * 8);
        #pragma unroll
        for (int i = 0; i < 8; ++i) h2s[tid * 8 + i] = bf2f(v[i]);
    }
    __syncthreads();
    if (tid < 8 * HATT) {
        int h = tid % HATT, sg = tid / HATT;
        float s = 0.f;
        for (int e = sg * 64; e < sg * 64 + 64; ++e) s += h2s[e] * WaHT[e * HATT + h];
        part[sg * HATT + h] = s;
    }
    __syncthreads();
    if (tid < HATT) {
        float s = 0.f;
        #pragma unroll
        for (int sg = 0; sg < 8; ++sg) s += part[sg * HATT + tid];
        hp[tid] = s;
    }
    __syncthreads();
    if (tid < LLEN) {
        float s = ba2v[0];
        const float* ep = ENCP + ((size_t)b * LLEN + tid) * HATT;
        #pragma unroll
        for (int h = 0; h < HATT; ++h)
            s += fmaxf(ep[h] + hp[h], 0.f) * Wa2[h];
        float v = tanhf(s);
        float m = v;
        for (int o = 32; o; o >>= 1) m = fmaxf(m, __shfl_xor(m, o));
        float e = __expf(v - m);
        float ss = e;
        for (int o = 32; o; o >>= 1) ss += __shfl_xor(ss, o);
        sl[tid] = e / ss;
    }
    __syncthreads();
    {
        float a = 0.f;
        const short* eb = ENCB + (size_t)b * LLEN * 512 + tid;
        #pragma unroll 8
        for (int l = 0; l < LLEN; ++l) a += sl[l] * bf2f(eb[l * 512]);
        ctx[(size_t)b * 512 + tid] = f2bf(a);
    }
    __syncthreads();
}

// ---------------------------------------------------------------------------
// Persistent megakernel: 8 independent per-XCD pipelines (32 rows each),
// discovered via HW_REG_XCC_ID + atomic registration. All state exchange is
// XCD-local: plain stores + sc0 loads, no fences. W2 parked in LDS; W1/W3/
// heads streamed (nt) from LLC. XCD-local 32-block barriers, relaxed polls.
// ---------------------------------------------------------------------------
__launch_bounds__(512)
__global__ void k_mega(
    const short* __restrict__ pack1, const short* __restrict__ pack2,
    const short* __restrict__ pack3, const short* __restrict__ ph1,
    const short* __restrict__ ph2,
    const float* __restrict__ b1p, const float* __restrict__ b2p,
    const float* __restrict__ b3p, const float* __restrict__ bl1,
    const float* __restrict__ bl2,
    const short* __restrict__ ET, const short* __restrict__ ENCB,
    const float* __restrict__ ENCP, const float* __restrict__ WaHT,
    const float* __restrict__ Wa2, const float* __restrict__ ba2v,
    const float* __restrict__ enc_c,
    short* __restrict__ h0a, short* __restrict__ h0b,
    short* __restrict__ h1a, short* __restrict__ h1b,
    short* __restrict__ h2a, short* __restrict__ h2b,
    short* __restrict__ ctx, short* __restrict__ hidden,
    int* __restrict__ cnt, unsigned long long* __restrict__ bar,
    float* __restrict__ out)
{
    __shared__ __align__(16) short wlds[65536];   // 128 KB: W2 slice (4 ct x 32 ks)
    __shared__ float gsc[2176];                   // 8.5 KB scratch (gates / partials)
    __shared__ float cst[3 * 512];                // persistent c-state
    __shared__ float h2s[512];
    __shared__ float part[8 * HATT];
    __shared__ float hp[HATT];
    __shared__ float sl[LLEN];
    __shared__ int sinfo[2];

    const int tid = threadIdx.x;

    // --- runtime XCD registration (no placement assumption) ---
    int xcd_reg;
    asm volatile("s_getreg_b32 %0, hwreg(HW_REG_XCC_ID)" : "=s"(xcd_reg));
    if (tid == 0) {
        sinfo[0] = xcd_reg;
        sinfo[1] = __hip_atomic_fetch_add(&cnt[xcd_reg], 1,
                                          __ATOMIC_RELAXED, __HIP_MEMORY_SCOPE_AGENT);
    }
    __syncthreads();
    const int myx = sinfo[0], lr = sinfo[1];      // lr: 0..31 within this XCD
    const int brow0 = myx * 32;

    // --- park W2 slice (this block's 64 gate-cols) in LDS ---
    {
        const bf16x8* s2v = (const bf16x8*)(pack2 + (size_t)lr * 65536);
        bf16x8* dst = (bf16x8*)wlds;
        for (int i = tid; i < 8192; i += 512)
            dst[i] = __builtin_nontemporal_load(&s2v[i]);
    }
    // --- c-state init ---
    {
        int row = tid >> 4, j = tid & 15;
        float cv = enc_c[(size_t)(brow0 + row) * 512 + lr * 16 + j];
        cst[tid] = cv; cst[512 + tid] = cv; cst[1024 + tid] = cv;
    }
    __syncthreads();

    int gen = 0;
    unsigned long long* mybar = &bar[myx * 16];
    auto gbar = [&]() {
        ++gen;
        asm volatile("s_waitcnt vmcnt(0)" ::: "memory");  // drain asm + plain stores
        __syncthreads();
        if (tid == 0) {
            __hip_atomic_fetch_add(mybar, 1ull,
                                   __ATOMIC_RELAXED, __HIP_MEMORY_SCOPE_AGENT);
            const unsigned long long target = 32ull * (unsigned long long)gen;
            while (__hip_atomic_load(mybar, __ATOMIC_RELAXED,
                                     __HIP_MEMORY_SCOPE_AGENT) < target)
                __builtin_amdgcn_s_sleep(2);
        }
        __syncthreads();
    };

    short* h0p[2] = { h0a, h0b };
    short* h1p[2] = { h1a, h1b };
    short* h2p[2] = { h2a, h2b };
    const int b_att = brow0 + lr;

    for (int t = 0; t < TLEN; ++t) {
        int p = t & 1, q = p ^ 1;
        // P1: LSTM1  A = [ET(t) | ctx(t-1) | h0(t-1)], K=1152, W1 streamed
        lstm_stage<36, 4, false>(pack1, wlds, b1p, ET + (size_t)t * BSZ * EMBD,
                                 ctx, h0p[p], cst, h0p[q], gsc, brow0, lr, tid);
        gbar();
        // P2: LSTM2  A = [h0(t) | h1(t-1)], W2 from LDS
        lstm_stage<32, 0, true>(pack2, wlds, b2p, nullptr,
                                h0p[q], h1p[p], cst + 512, h1p[q], gsc, brow0, lr, tid);
        gbar();
        // P3: LSTM3  A = [h1(t) | h2(t-1)], W3 streamed
        lstm_stage<32, 0, false>(pack3, wlds, b3p, nullptr,
                                 h1p[q], h2p[p], cst + 1024, h2p[q], gsc, brow0, lr, tid);
        gbar();
        // P4: attention (1 row/block) + head2(t-1) on blocks 9..17
        attn_stage(h2p[q], ENCB, ENCP, WaHT, Wa2, ba2v, ctx,
                   h2s, part, hp, sl, b_att, tid);
        if (t > 0 && lr >= 9 && lr < 18)
            head2_stage(ph2, bl2, hidden, out, t - 1, gsc, brow0, lr - 9, tid);
        gbar();
        // P5: head1 -> hidden(t)  (no trailing grid barrier; synced via bar1-3 of t+1)
        head1_stage(ph1, bl1, h2p[q], ctx, hidden, gsc, brow0, lr, tid);
    }
    gbar();
    if (lr >= 9 && lr < 18)
        head2_stage(ph2, bl2, hidden, out, TLEN - 1, gsc, brow0, lr - 9, tid);
}

// ---------------------------------------------------------------------------
extern "C" void kernel_launch(void* const* d_in, const int* in_sizes, int n_in,
                              void* d_out, int out_size, void* d_ws, size_t ws_size,
                              hipStream_t stream)
{
    const int*   act   = (const int*)d_in[0];
    const float* enc   = (const float*)d_in[1];
    const float* enc_h = (const float*)d_in[2];
    const float* enc_c = (const float*)d_in[3];
    const float* embW  = (const float*)d_in[4];
    const float* Wc    = (const float*)d_in[5];
    const float* bc    = (const float*)d_in[6];
    const float* Wih1  = (const float*)d_in[7];
    const float* Whh1  = (const float*)d_in[8];
    const float* bih1  = (const float*)d_in[9];
    const float* bhh1  = (const float*)d_in[10];
    const float* Wih2  = (const float*)d_in[11];
    const float* Whh2  = (const float*)d_in[12];
    const float* bih2  = (const float*)d_in[13];
    const float* bhh2  = (const float*)d_in[14];
    const float* Wih3  = (const float*)d_in[15];
    const float* Whh3  = (const float*)d_in[16];
    const float* bih3  = (const float*)d_in[17];
    const float* bhh3  = (const float*)d_in[18];
    const float* Wa1   = (const float*)d_in[19];
    const float* ba1   = (const float*)d_in[20];
    const float* Wa2   = (const float*)d_in[21];
    const float* ba2   = (const float*)d_in[22];
    const float* Wl1   = (const float*)d_in[23];
    const float* bl1   = (const float*)d_in[24];
    const float* Wl2   = (const float*)d_in[25];
    const float* bl2   = (const float*)d_in[26];
    float* out = (float*)d_out;

    char* cur = (char*)d_ws;
    auto alloc = [&](size_t bytes) {
        char* p = cur;
        cur += (bytes + 255) & ~(size_t)255;
        return p;
    };
    int* cnt = (int*)alloc(64);
    unsigned long long* bar = (unsigned long long*)alloc(8 * 16 * 8);
    short* pack1  = (short*)alloc((size_t)2048 * 1152 * 2);
    short* pack2  = (short*)alloc((size_t)2048 * 1024 * 2);
    short* pack3  = (short*)alloc((size_t)2048 * 1024 * 2);
    short* packh1 = (short*)alloc((size_t)512 * 1024 * 2);
    short* packh2 = (short*)alloc((size_t)192 * 512 * 2);
    // ENCB region doubles as W1f during prep (k_encb runs after k_pack1)
    short* ENCB   = (short*)alloc((size_t)BSZ * LLEN * 512 * 2);  // 16.8 MB
    float* W1f    = (float*)ENCB;                                  // 5.2 MB alias
    float* b1p    = (float*)alloc(2048 * 4);
    float* b2p    = (float*)alloc(2048 * 4);
    float* b3p    = (float*)alloc(2048 * 4);
    float* WaHT   = (float*)alloc(512 * HATT * 4);
    float* ENCP   = (float*)alloc((size_t)BSZ * LLEN * HATT * 4);
    short* ET     = (short*)alloc((size_t)TLEN * BSZ * EMBD * 2);
    const size_t SB = (size_t)BSZ * DH;
    short* h0a = (short*)alloc(SB * 2); short* h0b = (short*)alloc(SB * 2);
    short* h1a = (short*)alloc(SB * 2); short* h1b = (short*)alloc(SB * 2);
    short* h2a = (short*)alloc(SB * 2); short* h2b = (short*)alloc(SB * 2);
    short* ctx    = (short*)alloc(SB * 2);
    short* hidden = (short*)alloc(SB * 2);

    // ---- prep ----
    hipMemsetAsync(cnt, 0, 64, stream);
    hipMemsetAsync(bar, 0, 8 * 16 * 8, stream);
    k_fold<<<dim3(32, 10), 256, 0, stream>>>(Wih1, Wc, W1f);
    k_pack1<<<1152, 256, 0, stream>>>(W1f, Whh1, pack1);
    k_encb<<<8192, 256, 0, stream>>>(enc, ENCB);      // overwrites W1f region
    k_pack23<<<1024, 256, 0, stream>>>(Wih2, Whh2, pack2);
    k_pack23<<<1024, 256, 0, stream>>>(Wih3, Whh3, pack3);
    k_packh1<<<256, 256, 0, stream>>>(Wl1, packh1);
    k_packh2<<<48, 256, 0, stream>>>(Wl2, packh2);
    k_bias<<<8, 256, 0, stream>>>(Wih1, bc, bih1, bhh1, bih2, bhh2, bih3, bhh3,
                                  b1p, b2p, b3p);
    k_tr<<<(HATT * 512 + 255) / 256, 256, 0, stream>>>(WaHT, Wa1 + 512, HATT, 512, 1024, HATT);
    k_encp<<<BSZ, 256, 0, stream>>>(enc, Wa1, ba1, ENCP);
    k_embed<<<(TLEN * BSZ * EMBD) / 256, 256, 0, stream>>>(act, embW, ET);
    k_init<<<512, 256, 0, stream>>>(enc_h, h0a, h1a, h2a, ctx);

    // ---- persistent recurrent megakernel ----
    k_mega<<<256, 512, 0, stream>>>(
        pack1, pack2, pack3, packh1, packh2,
        b1p, b2p, b3p, bl1, bl2,
        ET, ENCB, ENCP, WaHT, Wa2, ba2,
        enc_c,
        h0a, h0b, h1a, h1b, h2a, h2b,
        ctx, hidden, cnt, bar, out);
}

// Round 7
// 9862.858 us; speedup vs baseline: 3.7749x; 1.0439x over previous
//
#include <hip/hip_runtime.h>
#include <math.h>

constexpr int BSZ  = 256;
constexpr int TLEN = 128;
constexpr int LLEN = 64;
constexpr int DH   = 512;
constexpr int EMBD = 128;
constexpr int ACTN = 129;
constexpr int HATT = 20;

typedef short bf16x8 __attribute__((ext_vector_type(8)));
typedef float f32x4  __attribute__((ext_vector_type(4)));

__device__ __forceinline__ short f2bf(float f) {
    unsigned u = __builtin_bit_cast(unsigned, f);
    u += 0x7fffu + ((u >> 16) & 1u);
    return (short)(u >> 16);
}
__device__ __forceinline__ float bf2f(short s) {
    unsigned u = ((unsigned)(unsigned short)s) << 16;
    return __builtin_bit_cast(float, u);
}

// ---------------------------------------------------------------------------
// Prep kernels (unchanged, proven)
// ---------------------------------------------------------------------------
__launch_bounds__(256)
__global__ void k_fold(const float* __restrict__ Wih1, const float* __restrict__ Wc,
                       float* __restrict__ W1f)
{
    __shared__ float at[64][33];
    __shared__ float bt[32][65];
    int tid = threadIdx.x;
    int tx = tid & 15, ty = tid >> 4;
    int n0 = blockIdx.x * 64, k0 = blockIdx.y * 64;
    float acc[4][4] = {};
    for (int m0 = 0; m0 < 512; m0 += 32) {
        for (int i = 0; i < 8; ++i) {
            int idx = tid + 256 * i;
            int nl = idx >> 5, ml = idx & 31;
            at[nl][ml] = Wih1[(size_t)(n0 + nl) * 512 + m0 + ml];
        }
        for (int i = 0; i < 8; ++i) {
            int idx = tid + 256 * i;
            int ml = idx >> 6, kl = idx & 63;
            bt[ml][kl] = Wc[(size_t)(m0 + ml) * 640 + k0 + kl];
        }
        __syncthreads();
        for (int m = 0; m < 32; ++m) {
            #pragma unroll
            for (int i = 0; i < 4; ++i) {
                float av = at[ty * 4 + i][m];
                #pragma unroll
                for (int j = 0; j < 4; ++j)
                    acc[i][j] += av * bt[m][tx * 4 + j];
            }
        }
        __syncthreads();
    }
    for (int i = 0; i < 4; ++i)
        for (int j = 0; j < 4; ++j)
            W1f[(size_t)(n0 + ty * 4 + i) * 640 + (k0 + tx * 4 + j)] = acc[i][j];
}

__global__ void k_pack23(const float* __restrict__ Wih, const float* __restrict__ Whh,
                         short* __restrict__ pack)
{
    int idx = blockIdx.x * 256 + threadIdx.x;       // 262144
    int lane = idx & 63;
    int ks = (idx >> 6) & 31;
    int nn = idx >> 11;
    int np = nn * 16 + (lane & 15);
    int k  = ks * 32 + ((lane >> 4) << 3);
    int n  = (np & 3) * 512 + (np >> 2);
    const float* src = (k < 512) ? (Wih + (size_t)n * 512 + k)
                                 : (Whh + (size_t)n * 512 + (k - 512));
    short* dst = pack + (size_t)idx * 8;
    #pragma unroll
    for (int i = 0; i < 8; ++i) dst[i] = f2bf(src[i]);
}

__global__ void k_pack1(const float* __restrict__ W1f, const float* __restrict__ Whh1,
                        short* __restrict__ pack)
{
    int idx = blockIdx.x * 256 + threadIdx.x;       // 294912
    int lane = idx & 63;
    int tmp = idx >> 6;
    int ks = tmp % 36;
    int nn = tmp / 36;
    int np = nn * 16 + (lane & 15);
    int k  = ks * 32 + ((lane >> 4) << 3);
    int n  = (np & 3) * 512 + (np >> 2);
    const float* src = (k < 640) ? (W1f + (size_t)n * 640 + k)
                                 : (Whh1 + (size_t)n * 512 + (k - 640));
    short* dst = pack + (size_t)idx * 8;
    #pragma unroll
    for (int i = 0; i < 8; ++i) dst[i] = f2bf(src[i]);
}

__global__ void k_packh1(const float* __restrict__ Wl1, short* __restrict__ pack)
{
    int idx = blockIdx.x * 256 + threadIdx.x;       // 65536
    int lane = idx & 63;
    int ks = (idx >> 6) & 31;
    int nn = idx >> 11;                              // <32
    int np = nn * 16 + (lane & 15);
    int k  = ks * 32 + ((lane >> 4) << 3);
    const float* src = Wl1 + (size_t)np * 1024 + k;
    short* dst = pack + (size_t)idx * 8;
    #pragma unroll
    for (int i = 0; i < 8; ++i) dst[i] = f2bf(src[i]);
}

__global__ void k_packh2(const float* __restrict__ Wl2, short* __restrict__ pack)
{
    int idx = blockIdx.x * 256 + threadIdx.x;       // 12288
    int lane = idx & 63;
    int ks = (idx >> 6) & 15;
    int nn = idx >> 10;                              // <12
    int np = nn * 16 + (lane & 15);
    int k  = ks * 32 + ((lane >> 4) << 3);
    short* dst = pack + (size_t)idx * 8;
    if (np < ACTN) {
        const float* src = Wl2 + (size_t)np * 512 + k;
        #pragma unroll
        for (int i = 0; i < 8; ++i) dst[i] = f2bf(src[i]);
    } else {
        #pragma unroll
        for (int i = 0; i < 8; ++i) dst[i] = 0;
    }
}

__global__ void k_bias(const float* __restrict__ Wih1, const float* __restrict__ bc,
                       const float* bih1, const float* bhh1,
                       const float* bih2, const float* bhh2,
                       const float* bih3, const float* bhh3,
                       float* b1p, float* b2p, float* b3p)
{
    int cp = blockIdx.x * 256 + threadIdx.x;        // 2048
    int n = (cp & 3) * 512 + (cp >> 2);
    float s = bih1[n] + bhh1[n];
    for (int m = 0; m < 512; ++m) s += Wih1[(size_t)n * 512 + m] * bc[m];
    b1p[cp] = s;
    b2p[cp] = bih2[n] + bhh2[n];
    b3p[cp] = bih3[n] + bhh3[n];
}

__global__ void k_tr(float* __restrict__ dst, const float* __restrict__ src,
                     int R, int C, int sld, int dld)
{
    int idx = blockIdx.x * 256 + threadIdx.x;
    if (idx >= R * C) return;
    int c = idx / R, r = idx - c * R;
    dst[c * dld + r] = src[r * sld + c];
}

__launch_bounds__(256)
__global__ void k_encp(const float* __restrict__ enc, const float* __restrict__ Wa1,
                       const float* __restrict__ ba1, float* __restrict__ ENCP)
{
    __shared__ float wa[HATT * 513];
    __shared__ float er[8][513];
    int b = blockIdx.x, tid = threadIdx.x;
    for (int idx = tid; idx < HATT * 512; idx += 256) {
        int h = idx >> 9, e = idx & 511;
        wa[h * 513 + e] = Wa1[h * 1024 + e];
    }
    __syncthreads();
    for (int c = 0; c < 8; ++c) {
        for (int i = 0; i < 16; ++i) {
            int idx = tid + 256 * i;
            int rr = idx >> 9, e = idx & 511;
            er[rr][e] = enc[((size_t)b * LLEN + c * 8 + rr) * 512 + e];
        }
        __syncthreads();
        if (tid < 8 * HATT) {
            int rr = tid & 7, h = tid >> 3;
            float s = 0.f;
            for (int e = 0; e < 512; ++e) s += er[rr][e] * wa[h * 513 + e];
            ENCP[((size_t)b * LLEN + c * 8 + rr) * HATT + h] = s + ba1[h];
        }
        __syncthreads();
    }
}

__global__ void k_embed(const int* __restrict__ act, const float* __restrict__ embW,
                        short* __restrict__ ET)
{
    int idx = blockIdx.x * 256 + threadIdx.x;       // 128*256*128
    int t = idx >> 15;
    int rem = idx & 32767;
    int b = rem >> 7, k = rem & 127;
    float v = 0.f;
    if (t > 0) v = embW[(size_t)act[b * TLEN + t - 1] * EMBD + k];
    ET[idx] = f2bf(v);
}

__global__ void k_encb(const float* __restrict__ enc, short* __restrict__ ENCB)
{
    int i = blockIdx.x * 256 + threadIdx.x;
    float4 v = *(const float4*)&enc[(size_t)i * 4];
    short4 o;
    o.x = f2bf(v.x); o.y = f2bf(v.y); o.z = f2bf(v.z); o.w = f2bf(v.w);
    *(short4*)&ENCB[(size_t)i * 4] = o;
}

__global__ void k_init(const float* __restrict__ eh,
                       short* h0, short* h1, short* h2, short* ctx)
{
    int i = blockIdx.x * 256 + threadIdx.x;         // 131072
    short hb = f2bf(eh[i]);
    h0[i] = hb; h1[i] = hb; h2[i] = hb; ctx[i] = 0;
}

// ---------------------------------------------------------------------------
// sc0 (L1-bypass) state loads; waitcnt bundled in-asm; sched_barrier per #18.
// ---------------------------------------------------------------------------
__device__ __forceinline__ void load_a8(const short* base,
    bf16x8& a0, bf16x8& a1, bf16x8& a2, bf16x8& a3,
    bf16x8& a4, bf16x8& a5, bf16x8& a6, bf16x8& a7)
{
    asm volatile(
        "global_load_dwordx4 %0, %8, off sc0\n\t"
        "global_load_dwordx4 %1, %8, off offset:64 sc0\n\t"
        "global_load_dwordx4 %2, %8, off offset:128 sc0\n\t"
        "global_load_dwordx4 %3, %8, off offset:192 sc0\n\t"
        "global_load_dwordx4 %4, %8, off offset:256 sc0\n\t"
        "global_load_dwordx4 %5, %8, off offset:320 sc0\n\t"
        "global_load_dwordx4 %6, %8, off offset:384 sc0\n\t"
        "global_load_dwordx4 %7, %8, off offset:448 sc0\n\t"
        "s_waitcnt vmcnt(0)"
        : "=&v"(a0), "=&v"(a1), "=&v"(a2), "=&v"(a3),
          "=&v"(a4), "=&v"(a5), "=&v"(a6), "=&v"(a7)
        : "v"(base) : "memory");
    __builtin_amdgcn_sched_barrier(0);
}

__device__ __forceinline__ void load_a4(const short* base,
    bf16x8& a0, bf16x8& a1, bf16x8& a2, bf16x8& a3)
{
    asm volatile(
        "global_load_dwordx4 %0, %4, off sc0\n\t"
        "global_load_dwordx4 %1, %4, off offset:64 sc0\n\t"
        "global_load_dwordx4 %2, %4, off offset:128 sc0\n\t"
        "global_load_dwordx4 %3, %4, off offset:192 sc0\n\t"
        "s_waitcnt vmcnt(0)"
        : "=&v"(a0), "=&v"(a1), "=&v"(a2), "=&v"(a3)
        : "v"(base) : "memory");
    __builtin_amdgcn_sched_barrier(0);
}

__device__ __forceinline__ bf16x8 load_a1(const short* p)
{
    bf16x8 r;
    asm volatile("global_load_dwordx4 %0, %1, off sc0\n\t"
                 "s_waitcnt vmcnt(0)"
                 : "=&v"(r) : "v"(p) : "memory");
    __builtin_amdgcn_sched_barrier(0);
    return r;
}

#define MFMA(af, bf, acc) \
    acc = __builtin_amdgcn_mfma_f32_16x16x32_bf16(af, bf, acc, 0, 0, 0)

// ---------------------------------------------------------------------------
// Shared LSTM epilogue: gates in gsc -> fused cell update (all 512 threads).
// ---------------------------------------------------------------------------
__device__ __forceinline__ void lstm_epilogue(
    const float* __restrict__ biasp, float* cstS, short* __restrict__ hout,
    float* gsc, int brow0, int lr, int tid)
{
    __syncthreads();
    int row = tid >> 4, j = tid & 15;
    float4 bv = *(const float4*)&biasp[(lr * 16 + j) * 4];
    float gi = gsc[row * 68 + j * 4 + 0] + bv.x;
    float gf = gsc[row * 68 + j * 4 + 1] + bv.y;
    float gg = gsc[row * 68 + j * 4 + 2] + bv.z;
    float go = gsc[row * 68 + j * 4 + 3] + bv.w;
    float c0 = cstS[tid];
    float si = 1.f / (1.f + __expf(-gi));
    float sf = 1.f / (1.f + __expf(-gf));
    float so = 1.f / (1.f + __expf(-go));
    float cn = sf * c0 + si * tanhf(gg);
    cstS[tid] = cn;
    hout[(size_t)(brow0 + row) * 512 + lr * 16 + j] = f2bf(so * tanhf(cn));
}

// ---------------------------------------------------------------------------
// LSTM1: waves 0-3 compute (W from registers + small streamed ET-part).
// A = [ET(t) (4ks, streamed B) | ctx (16ks) | h0_old (16ks)].
// ---------------------------------------------------------------------------
__device__ __forceinline__ void lstm1_reg(
    const bf16x8 (&w)[32], int wv, int lane,
    const short* __restrict__ pack1, const short* __restrict__ ET_t,
    const short* __restrict__ ctx, const short* __restrict__ h0old,
    const float* __restrict__ biasp, float* cstS, short* __restrict__ hout,
    float* gsc, int brow0, int lr, int tid)
{
    if (wv < 4) {
        const int rlane = lane & 15, kq = lane >> 4;
        const int ct = lr * 4 + wv;
        f32x4 acc0 = {}, acc1 = {};
        // ET part (ks 0..3): B streamed (L2-resident after first step)
        const short* bp = pack1 + ((size_t)(ct * 36) * 64 + lane) * 8;
        #pragma unroll
        for (int ks = 0; ks < 4; ++ks) {
            bf16x8 bf = *(const bf16x8*)(bp + ks * 512);
            bf16x8 af0 = *(const bf16x8*)(ET_t + (size_t)(brow0 + rlane) * EMBD + ks * 32 + kq * 8);
            bf16x8 af1 = *(const bf16x8*)(ET_t + (size_t)(brow0 + 16 + rlane) * EMBD + ks * 32 + kq * 8);
            MFMA(af0, bf, acc0);
            MFMA(af1, bf, acc1);
        }
        // main 32 ks: B from registers
        #pragma unroll
        for (int c = 0; c < 4; ++c) {
            const short* src = (c < 2) ? ctx : h0old;
            const int krel = (c & 1) * 8;
            const short* ab0 = src + (size_t)(brow0 + rlane) * 512 + krel * 32 + kq * 8;
            const short* ab1 = src + (size_t)(brow0 + 16 + rlane) * 512 + krel * 32 + kq * 8;
            bf16x8 a0, a1, a2, a3, a4, a5, a6, a7;
            load_a8(ab0, a0, a1, a2, a3, a4, a5, a6, a7);
            MFMA(a0, w[c * 8 + 0], acc0); MFMA(a1, w[c * 8 + 1], acc0);
            MFMA(a2, w[c * 8 + 2], acc0); MFMA(a3, w[c * 8 + 3], acc0);
            MFMA(a4, w[c * 8 + 4], acc0); MFMA(a5, w[c * 8 + 5], acc0);
            MFMA(a6, w[c * 8 + 6], acc0); MFMA(a7, w[c * 8 + 7], acc0);
            load_a8(ab1, a0, a1, a2, a3, a4, a5, a6, a7);
            MFMA(a0, w[c * 8 + 0], acc1); MFMA(a1, w[c * 8 + 1], acc1);
            MFMA(a2, w[c * 8 + 2], acc1); MFMA(a3, w[c * 8 + 3], acc1);
            MFMA(a4, w[c * 8 + 4], acc1); MFMA(a5, w[c * 8 + 5], acc1);
            MFMA(a6, w[c * 8 + 6], acc1); MFMA(a7, w[c * 8 + 7], acc1);
        }
        const int rlane2 = lane & 15, kq2 = lane >> 4;
        #pragma unroll
        for (int r = 0; r < 4; ++r) {
            gsc[(kq2 * 4 + r) * 68 + wv * 16 + rlane2] = acc0[r];
            gsc[(16 + kq2 * 4 + r) * 68 + wv * 16 + rlane2] = acc1[r];
        }
    }
    lstm_epilogue(biasp, cstS, hout, gsc, brow0, lr, tid);
}

// ---------------------------------------------------------------------------
// LSTM3: waves 4-7 compute (W from registers). A = [h1_new | h2_old].
// ---------------------------------------------------------------------------
__device__ __forceinline__ void lstm3_reg(
    const bf16x8 (&w)[32], int wv, int lane,
    const short* __restrict__ s1, const short* __restrict__ s2,
    const float* __restrict__ biasp, float* cstS, short* __restrict__ hout,
    float* gsc, int brow0, int lr, int tid)
{
    if (wv >= 4) {
        const int cw = wv - 4;
        const int rlane = lane & 15, kq = lane >> 4;
        f32x4 acc0 = {}, acc1 = {};
        #pragma unroll
        for (int c = 0; c < 4; ++c) {
            const short* src = (c < 2) ? s1 : s2;
            const int krel = (c & 1) * 8;
            const short* ab0 = src + (size_t)(brow0 + rlane) * 512 + krel * 32 + kq * 8;
            const short* ab1 = src + (size_t)(brow0 + 16 + rlane) * 512 + krel * 32 + kq * 8;
            bf16x8 a0, a1, a2, a3, a4, a5, a6, a7;
            load_a8(ab0, a0, a1, a2, a3, a4, a5, a6, a7);
            MFMA(a0, w[c * 8 + 0], acc0); MFMA(a1, w[c * 8 + 1], acc0);
            MFMA(a2, w[c * 8 + 2], acc0); MFMA(a3, w[c * 8 + 3], acc0);
            MFMA(a4, w[c * 8 + 4], acc0); MFMA(a5, w[c * 8 + 5], acc0);
            MFMA(a6, w[c * 8 + 6], acc0); MFMA(a7, w[c * 8 + 7], acc0);
            load_a8(ab1, a0, a1, a2, a3, a4, a5, a6, a7);
            MFMA(a0, w[c * 8 + 0], acc1); MFMA(a1, w[c * 8 + 1], acc1);
            MFMA(a2, w[c * 8 + 2], acc1); MFMA(a3, w[c * 8 + 3], acc1);
            MFMA(a4, w[c * 8 + 4], acc1); MFMA(a5, w[c * 8 + 5], acc1);
            MFMA(a6, w[c * 8 + 6], acc1); MFMA(a7, w[c * 8 + 7], acc1);
        }
        #pragma unroll
        for (int r = 0; r < 4; ++r) {
            gsc[(kq * 4 + r) * 68 + cw * 16 + rlane] = acc0[r];
            gsc[(16 + kq * 4 + r) * 68 + cw * 16 + rlane] = acc1[r];
        }
    }
    lstm_epilogue(biasp, cstS, hout, gsc, brow0, lr, tid);
}

// ---------------------------------------------------------------------------
// LSTM2: all 8 waves, W2 from LDS (r6 structure).
// ---------------------------------------------------------------------------
__device__ __forceinline__ void lstm2_lds(
    const short* wlds, const short* __restrict__ s1, const short* __restrict__ s2,
    const float* __restrict__ biasp, float* cstS, short* __restrict__ hout,
    float* gsc, int brow0, int lr, int tid)
{
    const int wave = tid >> 6, lane = tid & 63;
    const int wm = wave >> 2, wn = wave & 3;
    const int rlane = lane & 15, kq = lane >> 4;
    const int arow = brow0 + wm * 16 + rlane;
    f32x4 acc = {};
    #pragma unroll
    for (int c = 0; c < 4; ++c) {
        const int kss = c * 8;
        const short* src = (kss < 16) ? s1 : s2;
        const int krel = kss & 15;
        const short* abase = src + (size_t)arow * 512 + krel * 32 + kq * 8;
        const short* wb = wlds + ((wn * 32 + kss) * 64 + lane) * 8;
        bf16x8 b0 = *(const bf16x8*)(wb + 0 * 512);
        bf16x8 b1 = *(const bf16x8*)(wb + 1 * 512);
        bf16x8 b2 = *(const bf16x8*)(wb + 2 * 512);
        bf16x8 b3 = *(const bf16x8*)(wb + 3 * 512);
        bf16x8 b4 = *(const bf16x8*)(wb + 4 * 512);
        bf16x8 b5 = *(const bf16x8*)(wb + 5 * 512);
        bf16x8 b6 = *(const bf16x8*)(wb + 6 * 512);
        bf16x8 b7 = *(const bf16x8*)(wb + 7 * 512);
        bf16x8 a0, a1, a2, a3, a4, a5, a6, a7;
        load_a8(abase, a0, a1, a2, a3, a4, a5, a6, a7);
        MFMA(a0, b0, acc); MFMA(a1, b1, acc); MFMA(a2, b2, acc); MFMA(a3, b3, acc);
        MFMA(a4, b4, acc); MFMA(a5, b5, acc); MFMA(a6, b6, acc); MFMA(a7, b7, acc);
    }
    #pragma unroll
    for (int r = 0; r < 4; ++r)
        gsc[(wm * 16 + kq * 4 + r) * 68 + wn * 16 + rlane] = acc[r];
    lstm_epilogue(biasp, cstS, hout, gsc, brow0, lr, tid);
}

// ---------------------------------------------------------------------------
// head1: block's 16 cols, K=1024 split 4-way over wave pairs. Plain B loads.
// ---------------------------------------------------------------------------
__device__ __forceinline__ void head1_stage(
    const short* __restrict__ ph1, const float* __restrict__ bl1,
    const short* __restrict__ h2q, const short* __restrict__ ctx,
    short* __restrict__ hidden, float* gsc, int brow0, int lr, int tid)
{
    const int wave = tid >> 6, lane = tid & 63;
    const int wm = wave & 1, kq2 = wave >> 1;
    const int rlane = lane & 15, kq = lane >> 4;
    const int arow = brow0 + wm * 16 + rlane;
    const short* src = (kq2 < 2) ? h2q : ctx;
    const int krel = (kq2 & 1) * 8;
    const short* abase = src + (size_t)arow * 512 + krel * 32 + kq * 8;
    const short* wb = ph1 + ((size_t)(lr * 32 + kq2 * 8) * 64 + lane) * 8;
    f32x4 acc = {};
    #pragma unroll
    for (int g = 0; g < 2; ++g) {
        bf16x8 b0 = *(const bf16x8*)(wb + (g * 4 + 0) * 512);
        bf16x8 b1 = *(const bf16x8*)(wb + (g * 4 + 1) * 512);
        bf16x8 b2 = *(const bf16x8*)(wb + (g * 4 + 2) * 512);
        bf16x8 b3 = *(const bf16x8*)(wb + (g * 4 + 3) * 512);
        bf16x8 a0, a1, a2, a3;
        load_a4(abase + g * 128, a0, a1, a2, a3);
        MFMA(a0, b0, acc); MFMA(a1, b1, acc); MFMA(a2, b2, acc); MFMA(a3, b3, acc);
    }
    #pragma unroll
    for (int r = 0; r < 4; ++r)
        gsc[(kq2 * 2 + wm) * 256 + (kq * 4 + r) * 16 + rlane] = acc[r];
    __syncthreads();
    {
        float s = 0.f;
        #pragma unroll
        for (int k = 0; k < 4; ++k) s += gsc[(k * 2 + (tid >> 8)) * 256 + (tid & 255)];
        int row = (tid >> 8) * 16 + ((tid >> 4) & 15);
        int col = lr * 16 + (tid & 15);
        hidden[(size_t)(brow0 + row) * 512 + col] = f2bf(fmaxf(s + bl1[col], 0.f));
    }
    __syncthreads();
}

// ---------------------------------------------------------------------------
// head2 (blocks lr 9..17): n-tile of 16 cols, K=512. Plain B loads.
// ---------------------------------------------------------------------------
__device__ __forceinline__ void head2_stage(
    const short* __restrict__ ph2, const float* __restrict__ bl2,
    const short* __restrict__ hidden, float* __restrict__ out, int t,
    float* gsc, int brow0, int nt, int tid)
{
    const int wave = tid >> 6, lane = tid & 63;
    const int wm = wave & 1, kq4 = wave >> 1;
    const int rlane = lane & 15, kq = lane >> 4;
    const int arow = brow0 + wm * 16 + rlane;
    const short* abase = hidden + (size_t)arow * 512 + kq4 * 128 + kq * 8;
    const short* wb = ph2 + ((size_t)(nt * 16 + kq4 * 4) * 64 + lane) * 8;
    bf16x8 b0 = *(const bf16x8*)(wb + 0 * 512);
    bf16x8 b1 = *(const bf16x8*)(wb + 1 * 512);
    bf16x8 b2 = *(const bf16x8*)(wb + 2 * 512);
    bf16x8 b3 = *(const bf16x8*)(wb + 3 * 512);
    bf16x8 a0, a1, a2, a3;
    load_a4(abase, a0, a1, a2, a3);
    f32x4 acc = {};
    MFMA(a0, b0, acc); MFMA(a1, b1, acc); MFMA(a2, b2, acc); MFMA(a3, b3, acc);
    #pragma unroll
    for (int r = 0; r < 4; ++r)
        gsc[(kq4 * 2 + wm) * 256 + (kq * 4 + r) * 16 + rlane] = acc[r];
    __syncthreads();
    {
        float s = 0.f;
        #pragma unroll
        for (int k = 0; k < 4; ++k) s += gsc[(k * 2 + (tid >> 8)) * 256 + (tid & 255)];
        int row = (tid >> 8) * 16 + ((tid >> 4) & 15);
        int col = nt * 16 + (tid & 15);
        if (col < ACTN)
            out[((size_t)(brow0 + row) * TLEN + t) * ACTN + col] = s + bl2[col];
    }
}

// ---------------------------------------------------------------------------
// attention: one batch row per block (ENCB rows are L2-resident per XCD)
// ---------------------------------------------------------------------------
__device__ __forceinline__ void attn_stage(
    const short* __restrict__ h2q, const short* __restrict__ ENCB,
    const float* __restrict__ ENCP, const float* __restrict__ WaHT,
    const float* __restrict__ Wa2, const float* __restrict__ ba2v,
    short* __restrict__ ctx,
    float* h2s, float* part, float* hp, float* sl, int b, int tid)
{
    if (tid < 64) {
        bf16x8 v = load_a1(h2q + (size_t)b * 512 + tid * 8);
        #pragma unroll
        for (int i = 0; i < 8; ++i) h2s[tid * 8 + i] = bf2f(v[i]);
    }
    __syncthreads();
    if (tid < 8 * HATT) {
        int h = tid % HATT, sg = tid / HATT;
        float s = 0.f;
        for (int e = sg * 64; e < sg * 64 + 64; ++e) s += h2s[e] * WaHT[e * HATT + h];
        part[sg * HATT + h] = s;
    }
    __syncthreads();
    if (tid < HATT) {
        float s = 0.f;
        #pragma unroll
        for (int sg = 0; sg < 8; ++sg) s += part[sg * HATT + tid];
        hp[tid] = s;
    }
    __syncthreads();
    if (tid < LLEN) {
        float s = ba2v[0];
        const float* ep = ENCP + ((size_t)b * LLEN + tid) * HATT;
        #pragma unroll
        for (int h = 0; h < HATT; ++h)
            s += fmaxf(ep[h] + hp[h], 0.f) * Wa2[h];
        float v = tanhf(s);
        float m = v;
        for (int o = 32; o; o >>= 1) m = fmaxf(m, __shfl_xor(m, o));
        float e = __expf(v - m);
        float ss = e;
        for (int o = 32; o; o >>= 1) ss += __shfl_xor(ss, o);
        sl[tid] = e / ss;
    }
    __syncthreads();
    {
        float a = 0.f;
        const short* eb = ENCB + (size_t)b * LLEN * 512 + tid;
        #pragma unroll 8
        for (int l = 0; l < LLEN; ++l) a += sl[l] * bf2f(eb[l * 512]);
        ctx[(size_t)b * 512 + tid] = f2bf(a);
    }
    __syncthreads();
}

// ---------------------------------------------------------------------------
// Persistent megakernel. Per-XCD pipelines (32 rows each), XCD-local sync.
// W1/W3 live in per-wave REGISTERS (32 bf16x8 = 128 VGPR); W2 in LDS.
// Residual streams (head weights, ET, ENCB) are plain-cached -> L2-resident.
// ---------------------------------------------------------------------------
__launch_bounds__(512)
__global__ void k_mega(
    const short* __restrict__ pack1, const short* __restrict__ pack2,
    const short* __restrict__ pack3, const short* __restrict__ ph1,
    const short* __restrict__ ph2,
    const float* __restrict__ b1p, const float* __restrict__ b2p,
    const float* __restrict__ b3p, const float* __restrict__ bl1,
    const float* __restrict__ bl2,
    const short* __restrict__ ET, const short* __restrict__ ENCB,
    const float* __restrict__ ENCP, const float* __restrict__ WaHT,
    const float* __restrict__ Wa2, const float* __restrict__ ba2v,
    const float* __restrict__ enc_c,
    short* __restrict__ h0a, short* __restrict__ h0b,
    short* __restrict__ h1a, short* __restrict__ h1b,
    short* __restrict__ h2a, short* __restrict__ h2b,
    short* __restrict__ ctx, short* __restrict__ hidden,
    int* __restrict__ cnt, unsigned long long* __restrict__ bar,
    float* __restrict__ out)
{
    __shared__ __align__(16) short wlds[65536];   // 128 KB: W2 slice
    __shared__ float gsc[2176];
    __shared__ float cst[3 * 512];
    __shared__ float h2s[512];
    __shared__ float part[8 * HATT];
    __shared__ float hp[HATT];
    __shared__ float sl[LLEN];
    __shared__ int sinfo[2];

    const int tid = threadIdx.x;
    const int wv = tid >> 6, lane = tid & 63;

    // --- runtime XCD registration ---
    int xcd_reg;
    asm volatile("s_getreg_b32 %0, hwreg(HW_REG_XCC_ID)" : "=s"(xcd_reg));
    if (tid == 0) {
        sinfo[0] = xcd_reg;
        sinfo[1] = __hip_atomic_fetch_add(&cnt[xcd_reg], 1,
                                          __ATOMIC_RELAXED, __HIP_MEMORY_SCOPE_AGENT);
    }
    __syncthreads();
    const int myx = sinfo[0], lr = sinfo[1];
    const int brow0 = myx * 32;

    // --- park W2 slice in LDS (one-time, nt is fine) ---
    {
        const bf16x8* s2v = (const bf16x8*)(pack2 + (size_t)lr * 65536);
        bf16x8* dst = (bf16x8*)wlds;
        for (int i = tid; i < 8192; i += 512)
            dst[i] = __builtin_nontemporal_load(&s2v[i]);
    }
    // --- park W1 (waves 0-3, ctx|h part) / W3 (waves 4-7) in REGISTERS ---
    bf16x8 wreg[32];
    {
        const short* wsrc = (wv < 4)
            ? pack1 + ((size_t)((lr * 4 + wv) * 36 + 4) * 64 + lane) * 8
            : pack3 + ((size_t)((lr * 4 + (wv - 4)) * 32) * 64 + lane) * 8;
        #pragma unroll
        for (int i = 0; i < 32; ++i)
            wreg[i] = *(const bf16x8*)(wsrc + (size_t)i * 512);
    }
    // --- c-state init ---
    {
        int row = tid >> 4, j = tid & 15;
        float cv = enc_c[(size_t)(brow0 + row) * 512 + lr * 16 + j];
        cst[tid] = cv; cst[512 + tid] = cv; cst[1024 + tid] = cv;
    }
    __syncthreads();

    int gen = 0;
    unsigned long long* mybar = &bar[myx * 16];
    auto gbar = [&]() {
        ++gen;
        asm volatile("s_waitcnt vmcnt(0)" ::: "memory");
        __syncthreads();
        if (tid == 0) {
            __hip_atomic_fetch_add(mybar, 1ull,
                                   __ATOMIC_RELAXED, __HIP_MEMORY_SCOPE_AGENT);
            const unsigned long long target = 32ull * (unsigned long long)gen;
            while (__hip_atomic_load(mybar, __ATOMIC_RELAXED,
                                     __HIP_MEMORY_SCOPE_AGENT) < target)
                __builtin_amdgcn_s_sleep(2);
        }
        __syncthreads();
    };

    short* h0p[2] = { h0a, h0b };
    short* h1p[2] = { h1a, h1b };
    short* h2p[2] = { h2a, h2b };
    const int b_att = brow0 + lr;

    for (int t = 0; t < TLEN; ++t) {
        int p = t & 1, q = p ^ 1;
        // P1: LSTM1 (waves 0-3, W1 in regs)
        lstm1_reg(wreg, wv, lane, pack1, ET + (size_t)t * BSZ * EMBD,
                  ctx, h0p[p], b1p, cst, h0p[q], gsc, brow0, lr, tid);
        gbar();
        // P2: LSTM2 (all waves, W2 in LDS)
        lstm2_lds(wlds, h0p[q], h1p[p], b2p, cst + 512, h1p[q],
                  gsc, brow0, lr, tid);
        gbar();
        // P3: LSTM3 (waves 4-7, W3 in regs)
        lstm3_reg(wreg, wv, lane, h1p[q], h2p[p], b3p, cst + 1024, h2p[q],
                  gsc, brow0, lr, tid);
        gbar();
        // P4: attention + head2(t-1) on blocks 9..17
        attn_stage(h2p[q], ENCB, ENCP, WaHT, Wa2, ba2v, ctx,
                   h2s, part, hp, sl, b_att, tid);
        if (t > 0 && lr >= 9 && lr < 18)
            head2_stage(ph2, bl2, hidden, out, t - 1, gsc, brow0, lr - 9, tid);
        gbar();
        // P5: head1 -> hidden(t)  (synced via bars of t+1)
        head1_stage(ph1, bl1, h2p[q], ctx, hidden, gsc, brow0, lr, tid);
    }
    gbar();
    if (lr >= 9 && lr < 18)
        head2_stage(ph2, bl2, hidden, out, TLEN - 1, gsc, brow0, lr - 9, tid);
}

// ---------------------------------------------------------------------------
extern "C" void kernel_launch(void* const* d_in, const int* in_sizes, int n_in,
                              void* d_out, int out_size, void* d_ws, size_t ws_size,
                              hipStream_t stream)
{
    const int*   act   = (const int*)d_in[0];
    const float* enc   = (const float*)d_in[1];
    const float* enc_h = (const float*)d_in[2];
    const float* enc_c = (const float*)d_in[3];
    const float* embW  = (const float*)d_in[4];
    const float* Wc    = (const float*)d_in[5];
    const float* bc    = (const float*)d_in[6];
    const float* Wih1  = (const float*)d_in[7];
    const float* Whh1  = (const float*)d_in[8];
    const float* bih1  = (const float*)d_in[9];
    const float* bhh1  = (const float*)d_in[10];
    const float* Wih2  = (const float*)d_in[11];
    const float* Whh2  = (const float*)d_in[12];
    const float* bih2  = (const float*)d_in[13];
    const float* bhh2  = (const float*)d_in[14];
    const float* Wih3  = (const float*)d_in[15];
    const float* Whh3  = (const float*)d_in[16];
    const float* bih3  = (const float*)d_in[17];
    const float* bhh3  = (const float*)d_in[18];
    const float* Wa1   = (const float*)d_in[19];
    const float* ba1   = (const float*)d_in[20];
    const float* Wa2   = (const float*)d_in[21];
    const float* ba2   = (const float*)d_in[22];
    const float* Wl1   = (const float*)d_in[23];
    const float* bl1   = (const float*)d_in[24];
    const float* Wl2   = (const float*)d_in[25];
    const float* bl2   = (const float*)d_in[26];
    float* out = (float*)d_out;

    char* cur = (char*)d_ws;
    auto alloc = [&](size_t bytes) {
        char* p = cur;
        cur += (bytes + 255) & ~(size_t)255;
        return p;
    };
    int* cnt = (int*)alloc(64);
    unsigned long long* bar = (unsigned long long*)alloc(8 * 16 * 8);
    short* pack1  = (short*)alloc((size_t)2048 * 1152 * 2);
    short* pack2  = (short*)alloc((size_t)2048 * 1024 * 2);
    short* pack3  = (short*)alloc((size_t)2048 * 1024 * 2);
    short* packh1 = (short*)alloc((size_t)512 * 1024 * 2);
    short* packh2 = (short*)alloc((size_t)192 * 512 * 2);
    short* ENCB   = (short*)alloc((size_t)BSZ * LLEN * 512 * 2);  // 16.8 MB
    float* W1f    = (float*)ENCB;                                  // prep alias
    float* b1p    = (float*)alloc(2048 * 4);
    float* b2p    = (float*)alloc(2048 * 4);
    float* b3p    = (float*)alloc(2048 * 4);
    float* WaHT   = (float*)alloc(512 * HATT * 4);
    float* ENCP   = (float*)alloc((size_t)BSZ * LLEN * HATT * 4);
    short* ET     = (short*)alloc((size_t)TLEN * BSZ * EMBD * 2);
    const size_t SB = (size_t)BSZ * DH;
    short* h0a = (short*)alloc(SB * 2); short* h0b = (short*)alloc(SB * 2);
    short* h1a = (short*)alloc(SB * 2); short* h1b = (short*)alloc(SB * 2);
    short* h2a = (short*)alloc(SB * 2); short* h2b = (short*)alloc(SB * 2);
    short* ctx    = (short*)alloc(SB * 2);
    short* hidden = (short*)alloc(SB * 2);

    // ---- prep ----
    hipMemsetAsync(cnt, 0, 64, stream);
    hipMemsetAsync(bar, 0, 8 * 16 * 8, stream);
    k_fold<<<dim3(32, 10), 256, 0, stream>>>(Wih1, Wc, W1f);
    k_pack1<<<1152, 256, 0, stream>>>(W1f, Whh1, pack1);
    k_encb<<<8192, 256, 0, stream>>>(enc, ENCB);      // overwrites W1f region
    k_pack23<<<1024, 256, 0, stream>>>(Wih2, Whh2, pack2);
    k_pack23<<<1024, 256, 0, stream>>>(Wih3, Whh3, pack3);
    k_packh1<<<256, 256, 0, stream>>>(Wl1, packh1);
    k_packh2<<<48, 256, 0, stream>>>(Wl2, packh2);
    k_bias<<<8, 256, 0, stream>>>(Wih1, bc, bih1, bhh1, bih2, bhh2, bih3, bhh3,
                                  b1p, b2p, b3p);
    k_tr<<<(HATT * 512 + 255) / 256, 256, 0, stream>>>(WaHT, Wa1 + 512, HATT, 512, 1024, HATT);
    k_encp<<<BSZ, 256, 0, stream>>>(enc, Wa1, ba1, ENCP);
    k_embed<<<(TLEN * BSZ * EMBD) / 256, 256, 0, stream>>>(act, embW, ET);
    k_init<<<512, 256, 0, stream>>>(enc_h, h0a, h1a, h2a, ctx);

    // ---- persistent recurrent megakernel ----
    k_mega<<<256, 512, 0, stream>>>(
        pack1, pack2, pack3, packh1, packh2,
        b1p, b2p, b3p, bl1, bl2,
        ET, ENCB, ENCP, WaHT, Wa2, ba2,
        enc_c,
        h0a, h0b, h1a, h1b, h2a, h2b,
        ctx, hidden, cnt, bar, out);
}